// Round 8
// baseline (3314.449 us; speedup 1.0000x reference)
//
#include <hip/hip_runtime.h>
#include <stdint.h>
#include <math.h>

#define NSEQ   2048
#define VV     64
#define HID    512
#define LMAX   64
#define MINLEN 4

// ---------------- threefry2x32 (JAX/Random123, 20 rounds; KAT-verified) ----
__device__ __forceinline__ uint32_t rotl32(uint32_t x, int r) {
  return (x << r) | (x >> (32 - r));
}
__device__ __forceinline__ void threefry2x32(uint32_t ks0, uint32_t ks1,
                                             uint32_t x0, uint32_t x1,
                                             uint32_t &o0, uint32_t &o1) {
  uint32_t ks2 = ks0 ^ ks1 ^ 0x1BD11BDAu;
  x0 += ks0; x1 += ks1;
#define TF_RND(r) { x0 += x1; x1 = rotl32(x1, (r)); x1 ^= x0; }
  TF_RND(13) TF_RND(15) TF_RND(26) TF_RND(6)
  x0 += ks1; x1 += ks2 + 1u;
  TF_RND(17) TF_RND(29) TF_RND(16) TF_RND(24)
  x0 += ks2; x1 += ks0 + 2u;
  TF_RND(13) TF_RND(15) TF_RND(26) TF_RND(6)
  x0 += ks0; x1 += ks1 + 3u;
  TF_RND(17) TF_RND(29) TF_RND(16) TF_RND(24)
  x0 += ks1; x1 += ks2 + 4u;
  TF_RND(13) TF_RND(15) TF_RND(26) TF_RND(6)
  x0 += ks2; x1 += ks0 + 5u;
#undef TF_RND
  o0 = x0; o1 = x1;
}

// ---------------- wave helpers ----------------
__device__ __forceinline__ double dmax64(double v) {
#pragma unroll
  for (int off = 32; off >= 1; off >>= 1) {
    double o = __shfl_xor(v, off, 64);
    v = (o > v) ? o : v;
  }
  return v;
}
__device__ __forceinline__ double dsum64(double v) {
#pragma unroll
  for (int off = 32; off >= 1; off >>= 1) v += __shfl_xor(v, off, 64);
  return v;
}

// ---- precompute (f64 accumulate, f32 store): hconst = h0@Wh + b ; xw0 ----
__global__ void rnn_precompute(const float *__restrict__ input_init,
                               const float *__restrict__ hidden_init,
                               const float *__restrict__ Wx,
                               const float *__restrict__ Wh,
                               const float *__restrict__ b,
                               float *__restrict__ hconst,
                               float *__restrict__ xw0) {
  const int k = blockIdx.x * 64 + threadIdx.x;
  if (k >= HID) return;
  double acc = 0.0;
  for (int j = 0; j < HID; ++j)
    acc = fma((double)hidden_init[j], (double)Wh[(size_t)j * HID + k], acc);
  hconst[k] = (float)(acc + (double)b[k]);
  double a2 = 0.0;
  for (int j = 0; j < 2 * VV; ++j)
    a2 = fma((double)input_init[j], (double)Wx[(size_t)j * HID + k], a2);
  xw0[k] = (float)a2;
}

// --------- main sampler: 1 wave = 1 sequence, f64 numerics, f32 val -----
__global__ __launch_bounds__(64) void rnn_sampler(
    const float *__restrict__ Wx, const float *__restrict__ Wp,
    const float *__restrict__ bp,
    const float *__restrict__ hconst_g, const float *__restrict__ xw0_g,
    const int *__restrict__ two_arr, int n2,
    const int *__restrict__ one_arr, int n1,
    const int *__restrict__ var_arr, int nv,
    float *__restrict__ out) {
  __shared__ double smh[HID];

  const int lane = threadIdx.x;   // = token id v, and k-slot owner
  const int n    = blockIdx.x;    // sequence id

  bool isTwo = false, isOne = false, isVar = false;
  for (int j = 0; j < n2; ++j) isTwo |= (lane == two_arr[j]);
  for (int j = 0; j < n1; ++j) isOne |= (lane == one_arr[j]);
  for (int j = 0; j < nv; ++j) isVar |= (lane == var_arr[j]);
  const unsigned long long two_mask = __ballot(isTwo);
  const unsigned long long one_mask = __ballot(isOne);
  const unsigned long long var_mask = __ballot(isVar);
  const bool two_v   = (two_mask >> lane) & 1ull;
  const bool one_v   = (one_mask >> lane) & 1ull;
  const bool zero_v  = !(two_v || one_v);
  const bool const_v = zero_v && !((var_mask >> lane) & 1ull);
  const double bp_v  = (double)bp[lane];

  double hc[8], xw[8];
#pragma unroll
  for (int i = 0; i < 8; ++i) {
    hc[i] = (double)hconst_g[i * 64 + lane];
    xw[i] = (double)xw0_g[i * 64 + lane];
  }

  int myseq = -1;                 // lane L holds seq[L]
  int counters = 1;
  bool alive = true, hasvar = false;
  double accE = 0.0, accLP = 0.0;
  int lenacc = 0;
  int parent = -1, sib = -1;

  for (int t = 0; t < LMAX; ++t) {
    // ---- Phase A: h_k = tanh((x@Wx)_k + hconst_k)  (f64)
#pragma unroll
    for (int i = 0; i < 8; ++i) {
      double ax;
      if (t == 0) {
        ax = xw[i];
      } else {
        ax = 0.0;
        if (parent >= 0) ax = (double)Wx[(size_t)parent * HID + i * 64 + lane];
        if (sib >= 0)
          ax += (double)Wx[(size_t)(VV + sib) * HID + i * 64 + lane];
      }
      smh[i * 64 + lane] = tanh(ax + hc[i]);
    }
    __syncthreads();

    // ---- Phase B: logit[lane] = Σ_k h_k · Wp[k][lane]  (f64)
    double pacc[8];
#pragma unroll
    for (int i = 0; i < 8; ++i) pacc[i] = 0.0;
#pragma unroll 4
    for (int j = 0; j < 64; ++j) {
#pragma unroll
      for (int i = 0; i < 8; ++i) {
        pacc[i] = fma(smh[i * 64 + j],
                      (double)Wp[(size_t)(i * 64 + j) * VV + lane], pacc[i]);
      }
    }
    double acc = ((pacc[0] + pacc[1]) + (pacc[2] + pacc[3])) +
                 ((pacc[4] + pacc[5]) + (pacc[6] + pacc[7]));
    __syncthreads();

    // ---- Phase C: softmax / mask / sample / state update  (f64)
    {
      const double lraw = acc + bp_v;
      const double mx = dmax64(lraw);
      const double e  = exp(lraw - mx);
      const double S1 = dsum64(e);
      const double p1 = e / S1;

      const int tot = t + counters;
      bool keep = true;
      if (zero_v && tot < MINLEN) keep = false;
      if (two_v && (tot + 2 > LMAX)) keep = false;
      if (one_v && (tot + 1 > LMAX)) keep = false;
      if (const_v && !hasvar && (counters == 1)) keep = false;

      const double p  = keep ? p1 : 0.0;
      const double S2 = dsum64(p);
      const double p2 = p / fmax(S2, 1e-30);
      const bool   pos = p2 > 0.0;
      const double lg  = pos ? log(p2) : 0.0;
      const double lgi = pos ? lg : -__builtin_inf();

      // gumbel bits: JAX partitionable threefry, 32-bit output =
      //   XOR of both output words of threefry(fold_in(key(1234),t), (0, idx))
      const uint32_t idx = (uint32_t)((n << 6) + lane);
      uint32_t kt0, kt1;
      threefry2x32(0u, 1234u, 0u, (uint32_t)t, kt0, kt1);
      uint32_t b0, b1;
      threefry2x32(kt0, kt1, 0u, idx, b0, b1);
      const uint32_t bits = b0 ^ b1;      // <-- the single change this round
      const float f = __uint_as_float((bits >> 9) | 0x3f800000u) - 1.0f;
      const double u = (f == 0.f) ? (double)1.17549435e-38f : (double)f;
      const double g = -log(-log(u));

      // final value quantized to f32 (refs compare f32), first-index tie-break
      const float val32 = (float)(g + lgi);

      float bv = val32; int bi = lane;
#pragma unroll
      for (int off = 32; off >= 1; off >>= 1) {
        float ov = __shfl_xor(bv, off, 64);
        int   oi = __shfl_xor(bi, off, 64);
        if (ov > bv || (ov == bv && oi < bi)) { bv = ov; bi = oi; }
      }
      const int token = bi;
      const double lp  = __shfl(lg, token, 64);
      const double ent = dsum64(pos ? (-p2 * lg) : 0.0);

      const bool tk2 = (two_mask >> token) & 1ull;
      const bool tk1 = (one_mask >> token) & 1ull;
      counters += -1 + 2 * (int)tk2 + (int)tk1;
      alive = alive && (counters > 0);
      if (alive) { accE += ent; accLP += lp; lenacc++; }
      hasvar = hasvar || ((var_mask >> token) & 1ull);

      if (lane == t) myseq = token;

      // parent/sibling: reversed inclusive prefix-sum of (arity-1)
      int a = 0;
      if (lane <= t) {
        const int tk = __shfl(myseq, t - lane, 64);
        a = -1 + 2 * (int)((two_mask >> tk) & 1ull) +
            (int)((one_mask >> tk) & 1ull);
      }
      int c = a;
#pragma unroll
      for (int off = 1; off < 64; off <<= 1) {
        int o = __shfl_up(c, off, 64);
        if (lane >= off) c += o;
      }
      const bool hit = (lane <= t) && (c == 0);
      const unsigned long long hb = __ballot(hit);
      if (tk2 || tk1) { parent = token; sib = -1; }
      else if (hb == 0ull) { parent = -1; sib = -1; }
      else {
        const int kf = __ffsll((long long)hb) - 1;
        parent = __shfl(myseq, t - kf, 64);
        sib = (kf == 0) ? -1 : __shfl(myseq, t - kf + 1, 64);
      }
    }
  }

  // ---- outputs (f32): [seq (2048x64) | lengths | ents | lps]
  out[(size_t)n * LMAX + lane] = (float)myseq;
  if (lane == 0) {
    out[(size_t)NSEQ * LMAX + n]       = (float)(lenacc + 1);
    out[(size_t)NSEQ * (LMAX + 1) + n] = (float)accE;
    out[(size_t)NSEQ * (LMAX + 2) + n] = (float)accLP;
  }
}

extern "C" void kernel_launch(void *const *d_in, const int *in_sizes, int n_in,
                              void *d_out, int out_size, void *d_ws, size_t ws_size,
                              hipStream_t stream) {
  (void)n_in; (void)out_size; (void)ws_size;
  const float *input_init  = (const float *)d_in[0];
  const float *hidden_init = (const float *)d_in[1];
  const float *Wx = (const float *)d_in[2];
  const float *Wh = (const float *)d_in[3];
  const float *b  = (const float *)d_in[4];
  const float *Wp = (const float *)d_in[5];
  const float *bp = (const float *)d_in[6];
  const int *two_arr = (const int *)d_in[7];
  const int *one_arr = (const int *)d_in[8];
  const int *var_arr = (const int *)d_in[9];
  const int n2 = in_sizes[7], n1 = in_sizes[8], nv = in_sizes[9];

  float *hconst = (float *)d_ws;          // 4 KB total ws, proven safe
  float *xw0    = hconst + HID;
  float *out    = (float *)d_out;

  rnn_precompute<<<8, 64, 0, stream>>>(input_init, hidden_init, Wx, Wh, b,
                                       hconst, xw0);
  rnn_sampler<<<NSEQ, 64, 0, stream>>>(Wx, Wp, bp, hconst, xw0,
                                       two_arr, n2, one_arr, n1,
                                       var_arr, nv, out);
}

// Round 9
// 794.809 us; speedup vs baseline: 4.1701x; 4.1701x over previous
//
#include <hip/hip_runtime.h>
#include <stdint.h>
#include <math.h>

#define NSEQ   2048
#define VV     64
#define HID    512
#define LMAX   64
#define MINLEN 4
#define SPB    8      // sequences per block = waves per block
#define NTHR   512    // 8 waves
#define HSTR   (HID + 8)   // LDS row stride for h (bank-decorrelating pad)

// ---------------- threefry2x32 (JAX/Random123, 20 rounds; KAT-verified) ----
__device__ __forceinline__ uint32_t rotl32(uint32_t x, int r) {
  return (x << r) | (x >> (32 - r));
}
__device__ __forceinline__ void threefry2x32(uint32_t ks0, uint32_t ks1,
                                             uint32_t x0, uint32_t x1,
                                             uint32_t &o0, uint32_t &o1) {
  uint32_t ks2 = ks0 ^ ks1 ^ 0x1BD11BDAu;
  x0 += ks0; x1 += ks1;
#define TF_RND(r) { x0 += x1; x1 = rotl32(x1, (r)); x1 ^= x0; }
  TF_RND(13) TF_RND(15) TF_RND(26) TF_RND(6)
  x0 += ks1; x1 += ks2 + 1u;
  TF_RND(17) TF_RND(29) TF_RND(16) TF_RND(24)
  x0 += ks2; x1 += ks0 + 2u;
  TF_RND(13) TF_RND(15) TF_RND(26) TF_RND(6)
  x0 += ks0; x1 += ks1 + 3u;
  TF_RND(17) TF_RND(29) TF_RND(16) TF_RND(24)
  x0 += ks1; x1 += ks2 + 4u;
  TF_RND(13) TF_RND(15) TF_RND(26) TF_RND(6)
  x0 += ks2; x1 += ks0 + 5u;
#undef TF_RND
  o0 = x0; o1 = x1;
}

// ---------------- wave helpers ----------------
__device__ __forceinline__ float wmaxf64(float v) {
#pragma unroll
  for (int off = 32; off >= 1; off >>= 1) v = fmaxf(v, __shfl_xor(v, off, 64));
  return v;
}
__device__ __forceinline__ double dsum64(double v) {
#pragma unroll
  for (int off = 32; off >= 1; off >>= 1) v += __shfl_xor(v, off, 64);
  return v;
}

// ---- precompute (f64 accumulate, f32 store): hconst = h0@Wh + b ; xw0 ----
__global__ void rnn_precompute(const float *__restrict__ input_init,
                               const float *__restrict__ hidden_init,
                               const float *__restrict__ Wx,
                               const float *__restrict__ Wh,
                               const float *__restrict__ b,
                               float *__restrict__ hconst,
                               float *__restrict__ xw0) {
  const int k = blockIdx.x * 64 + threadIdx.x;
  if (k >= HID) return;
  double acc = 0.0;
  for (int j = 0; j < HID; ++j)
    acc = fma((double)hidden_init[j], (double)Wh[(size_t)j * HID + k], acc);
  hconst[k] = (float)(acc + (double)b[k]);
  double a2 = 0.0;
  for (int j = 0; j < 2 * VV; ++j)
    a2 = fma((double)input_init[j], (double)Wx[(size_t)j * HID + k], a2);
  xw0[k] = (float)a2;
}

// --------- main sampler: 8 waves = 8 seqs per block, Wp in registers -----
__global__ __launch_bounds__(NTHR) void rnn_sampler(
    const float *__restrict__ Wx, const float *__restrict__ Wp,
    const float *__restrict__ bp,
    const float *__restrict__ hconst_g, const float *__restrict__ xw0_g,
    const int *__restrict__ two_arr, int n2,
    const int *__restrict__ one_arr, int n1,
    const int *__restrict__ var_arr, int nv,
    float *__restrict__ out) {
  __shared__ float smh[SPB][HSTR];      // h per seq (f32)
  __shared__ float smp[SPB][SPB][VV];   // partial logits [kslice wave][seq][v]

  const int tid  = threadIdx.x;
  const int lane = tid & 63;            // = token id v, and k-slot owner
  const int w    = tid >> 6;            // wave id = local seq id
  const int n    = blockIdx.x * SPB + w; // global sequence id

  // token-class bitmasks (lane == token id)
  bool isTwo = false, isOne = false, isVar = false;
  for (int j = 0; j < n2; ++j) isTwo |= (lane == two_arr[j]);
  for (int j = 0; j < n1; ++j) isOne |= (lane == one_arr[j]);
  for (int j = 0; j < nv; ++j) isVar |= (lane == var_arr[j]);
  const unsigned long long two_mask = __ballot(isTwo);
  const unsigned long long one_mask = __ballot(isOne);
  const unsigned long long var_mask = __ballot(isVar);
  const bool two_v   = (two_mask >> lane) & 1ull;
  const bool one_v   = (one_mask >> lane) & 1ull;
  const bool zero_v  = !(two_v || one_v);
  const bool const_v = zero_v && !((var_mask >> lane) & 1ull);
  const float bp_v   = bp[lane];

  // per-lane slices of hconst / xw0 : index k = 64*i + lane (f32)
  float hc[8], xw[8];
#pragma unroll
  for (int i = 0; i < 8; ++i) {
    hc[i] = hconst_g[i * 64 + lane];
    xw[i] = xw0_g[i * 64 + lane];
  }

  // GEMM lane roles: wave w owns K-slice [64w, 64w+64); lane = ksub(4)×vg(16)
  const int vg    = lane & 15;
  const int ksub  = lane >> 4;
  const int kbase = w * 64 + ksub * 16;

  // Wp fragment in registers: rows kbase..kbase+15, cols 4vg..4vg+3 (64 VGPR)
  float4 wpr[16];
#pragma unroll
  for (int kk = 0; kk < 16; ++kk)
    wpr[kk] = *(const float4 *)&Wp[(size_t)(kbase + kk) * VV + vg * 4];

  int myseq = -1;                 // lane L holds seq[L] (this wave's seq)
  int counters = 1;
  bool alive = true, hasvar = false;
  double accE = 0.0, accLP = 0.0;
  int lenacc = 0;
  int parent = -1, sib = -1;

  for (int t = 0; t < LMAX; ++t) {
    // ---- Phase A: wave w computes h for seq w; k = 64*i + lane
#pragma unroll
    for (int i = 0; i < 8; ++i) {
      float ax;
      if (t == 0) {
        ax = xw[i];
      } else {
        ax = 0.f;
        if (parent >= 0) ax = Wx[(size_t)parent * HID + i * 64 + lane];
        if (sib >= 0) ax += Wx[(size_t)(VV + sib) * HID + i * 64 + lane];
      }
      smh[w][i * 64 + lane] = (float)tanh((double)(ax + hc[i]));
    }
    __syncthreads();

    // ---- Phase B: partial logits for ALL 8 seqs, Wp from registers
    {
      float acc[SPB][4];
#pragma unroll
      for (int s = 0; s < SPB; ++s) {
        acc[s][0] = 0.f; acc[s][1] = 0.f; acc[s][2] = 0.f; acc[s][3] = 0.f;
      }
#pragma unroll
      for (int k4 = 0; k4 < 4; ++k4) {
#pragma unroll
        for (int s = 0; s < SPB; ++s) {
          float4 hv = *(const float4 *)&smh[s][kbase + k4 * 4];
          acc[s][0] = fmaf(hv.x, wpr[k4*4+0].x, acc[s][0]);
          acc[s][0] = fmaf(hv.y, wpr[k4*4+1].x, acc[s][0]);
          acc[s][0] = fmaf(hv.z, wpr[k4*4+2].x, acc[s][0]);
          acc[s][0] = fmaf(hv.w, wpr[k4*4+3].x, acc[s][0]);
          acc[s][1] = fmaf(hv.x, wpr[k4*4+0].y, acc[s][1]);
          acc[s][1] = fmaf(hv.y, wpr[k4*4+1].y, acc[s][1]);
          acc[s][1] = fmaf(hv.z, wpr[k4*4+2].y, acc[s][1]);
          acc[s][1] = fmaf(hv.w, wpr[k4*4+3].y, acc[s][1]);
          acc[s][2] = fmaf(hv.x, wpr[k4*4+0].z, acc[s][2]);
          acc[s][2] = fmaf(hv.y, wpr[k4*4+1].z, acc[s][2]);
          acc[s][2] = fmaf(hv.z, wpr[k4*4+2].z, acc[s][2]);
          acc[s][2] = fmaf(hv.w, wpr[k4*4+3].z, acc[s][2]);
          acc[s][3] = fmaf(hv.x, wpr[k4*4+0].w, acc[s][3]);
          acc[s][3] = fmaf(hv.y, wpr[k4*4+1].w, acc[s][3]);
          acc[s][3] = fmaf(hv.z, wpr[k4*4+2].w, acc[s][3]);
          acc[s][3] = fmaf(hv.w, wpr[k4*4+3].w, acc[s][3]);
        }
      }
      // reduce across ksub (lane bits 4,5); lanes 0-15 hold the slice sums
#pragma unroll
      for (int s = 0; s < SPB; ++s) {
#pragma unroll
        for (int c = 0; c < 4; ++c) {
          acc[s][c] += __shfl_xor(acc[s][c], 16, 64);
          acc[s][c] += __shfl_xor(acc[s][c], 32, 64);
        }
      }
      if (ksub == 0) {
#pragma unroll
        for (int s = 0; s < SPB; ++s) {
          float4 v;
          v.x = acc[s][0]; v.y = acc[s][1]; v.z = acc[s][2]; v.w = acc[s][3];
          *(float4 *)&smp[w][s][vg * 4] = v;
        }
      }
    }
    __syncthreads();

    // ---- Phase C: softmax / mask / sample / state update (seq = w)
    {
      float lsum = 0.f;
#pragma unroll
      for (int ww = 0; ww < SPB; ++ww) lsum += smp[ww][w][lane];
      const float lraw = lsum + bp_v;

      const float mx = wmaxf64(lraw);
      const double e  = exp((double)(lraw - mx));
      const double S1 = dsum64(e);
      const double p1 = e / S1;

      const int tot = t + counters;
      bool keep = true;
      if (zero_v && tot < MINLEN) keep = false;
      if (two_v && (tot + 2 > LMAX)) keep = false;
      if (one_v && (tot + 1 > LMAX)) keep = false;
      if (const_v && !hasvar && (counters == 1)) keep = false;

      const double p  = keep ? p1 : 0.0;
      const double S2 = dsum64(p);
      const double p2 = p / fmax(S2, 1e-30);
      const bool   pos = p2 > 0.0;
      const double lg  = pos ? log(p2) : 0.0;
      const double lgi = pos ? lg : -__builtin_inf();

      // gumbel bits: partitionable threefry, bits = out0 ^ out1 (verified R8)
      const uint32_t idx = (uint32_t)((n << 6) + lane);
      uint32_t kt0, kt1;
      threefry2x32(0u, 1234u, 0u, (uint32_t)t, kt0, kt1);
      uint32_t b0, b1;
      threefry2x32(kt0, kt1, 0u, idx, b0, b1);
      const uint32_t bits = b0 ^ b1;
      const float f = __uint_as_float((bits >> 9) | 0x3f800000u) - 1.0f;
      const double u = (f == 0.f) ? (double)1.17549435e-38f : (double)f;
      const double g = -log(-log(u));

      const float val32 = (float)(g + lgi);

      float bv = val32; int bi = lane;
#pragma unroll
      for (int off = 32; off >= 1; off >>= 1) {
        float ov = __shfl_xor(bv, off, 64);
        int   oi = __shfl_xor(bi, off, 64);
        if (ov > bv || (ov == bv && oi < bi)) { bv = ov; bi = oi; }
      }
      const int token = bi;
      const double lp  = __shfl(lg, token, 64);
      const double ent = dsum64(pos ? (-p2 * lg) : 0.0);

      const bool tk2 = (two_mask >> token) & 1ull;
      const bool tk1 = (one_mask >> token) & 1ull;
      counters += -1 + 2 * (int)tk2 + (int)tk1;
      alive = alive && (counters > 0);
      if (alive) { accE += ent; accLP += lp; lenacc++; }
      hasvar = hasvar || ((var_mask >> token) & 1ull);

      if (lane == t) myseq = token;

      // parent/sibling: reversed inclusive prefix-sum of (arity-1)
      int a = 0;
      if (lane <= t) {
        const int tk = __shfl(myseq, t - lane, 64);
        a = -1 + 2 * (int)((two_mask >> tk) & 1ull) +
            (int)((one_mask >> tk) & 1ull);
      }
      int c = a;
#pragma unroll
      for (int off = 1; off < 64; off <<= 1) {
        int o = __shfl_up(c, off, 64);
        if (lane >= off) c += o;
      }
      const bool hit = (lane <= t) && (c == 0);
      const unsigned long long hb = __ballot(hit);
      if (tk2 || tk1) { parent = token; sib = -1; }
      else if (hb == 0ull) { parent = -1; sib = -1; }
      else {
        const int kf = __ffsll((long long)hb) - 1;
        parent = __shfl(myseq, t - kf, 64);
        sib = (kf == 0) ? -1 : __shfl(myseq, t - kf + 1, 64);
      }
    }
    __syncthreads();   // protect smp (and smh) before next iteration
  }

  // ---- outputs (f32): [seq (2048x64) | lengths | ents | lps]
  out[(size_t)n * LMAX + lane] = (float)myseq;
  if (lane == 0) {
    out[(size_t)NSEQ * LMAX + n]       = (float)(lenacc + 1);
    out[(size_t)NSEQ * (LMAX + 1) + n] = (float)accE;
    out[(size_t)NSEQ * (LMAX + 2) + n] = (float)accLP;
  }
}

extern "C" void kernel_launch(void *const *d_in, const int *in_sizes, int n_in,
                              void *d_out, int out_size, void *d_ws, size_t ws_size,
                              hipStream_t stream) {
  (void)n_in; (void)out_size; (void)ws_size;
  const float *input_init  = (const float *)d_in[0];
  const float *hidden_init = (const float *)d_in[1];
  const float *Wx = (const float *)d_in[2];
  const float *Wh = (const float *)d_in[3];
  const float *b  = (const float *)d_in[4];
  const float *Wp = (const float *)d_in[5];
  const float *bp = (const float *)d_in[6];
  const int *two_arr = (const int *)d_in[7];
  const int *one_arr = (const int *)d_in[8];
  const int *var_arr = (const int *)d_in[9];
  const int n2 = in_sizes[7], n1 = in_sizes[8], nv = in_sizes[9];

  float *hconst = (float *)d_ws;
  float *xw0    = hconst + HID;
  float *out    = (float *)d_out;

  rnn_precompute<<<8, 64, 0, stream>>>(input_init, hidden_init, Wx, Wh, b,
                                       hconst, xw0);
  rnn_sampler<<<NSEQ / SPB, NTHR, 0, stream>>>(Wx, Wp, bp, hconst, xw0,
                                               two_arr, n2, one_arr, n1,
                                               var_arr, nv, out);
}

// Round 10
// 492.516 us; speedup vs baseline: 6.7296x; 1.6138x over previous
//
#include <hip/hip_runtime.h>
#include <stdint.h>
#include <math.h>

#define NSEQ   2048
#define VV     64
#define HID    512
#define LMAX   64
#define MINLEN 4
#define SPB    8      // sequences per block = waves per block
#define NTHR   512    // 8 waves
#define HSTR   (HID + 8)   // LDS row stride for h
#define H_ROWS 4226        // 65*65 (parent,sib) rows + 1 row for t==0
#define H_T0   4225

// ---------------- threefry2x32 (JAX/Random123, 20 rounds; KAT-verified) ----
__device__ __forceinline__ uint32_t rotl32(uint32_t x, int r) {
  return (x << r) | (x >> (32 - r));
}
__device__ __forceinline__ void threefry2x32(uint32_t ks0, uint32_t ks1,
                                             uint32_t x0, uint32_t x1,
                                             uint32_t &o0, uint32_t &o1) {
  uint32_t ks2 = ks0 ^ ks1 ^ 0x1BD11BDAu;
  x0 += ks0; x1 += ks1;
#define TF_RND(r) { x0 += x1; x1 = rotl32(x1, (r)); x1 ^= x0; }
  TF_RND(13) TF_RND(15) TF_RND(26) TF_RND(6)
  x0 += ks1; x1 += ks2 + 1u;
  TF_RND(17) TF_RND(29) TF_RND(16) TF_RND(24)
  x0 += ks2; x1 += ks0 + 2u;
  TF_RND(13) TF_RND(15) TF_RND(26) TF_RND(6)
  x0 += ks0; x1 += ks1 + 3u;
  TF_RND(17) TF_RND(29) TF_RND(16) TF_RND(24)
  x0 += ks1; x1 += ks2 + 4u;
  TF_RND(13) TF_RND(15) TF_RND(26) TF_RND(6)
  x0 += ks2; x1 += ks0 + 5u;
#undef TF_RND
  o0 = x0; o1 = x1;
}

// ---------------- wave helpers ----------------
__device__ __forceinline__ float wmaxf64(float v) {
#pragma unroll
  for (int off = 32; off >= 1; off >>= 1) v = fmaxf(v, __shfl_xor(v, off, 64));
  return v;
}
__device__ __forceinline__ double dsum64(double v) {
#pragma unroll
  for (int off = 32; off >= 1; off >>= 1) v += __shfl_xor(v, off, 64);
  return v;
}

// ---- precompute (f64 accumulate, f32 store): hconst = h0@Wh + b ; xw0 ----
__global__ void rnn_precompute(const float *__restrict__ input_init,
                               const float *__restrict__ hidden_init,
                               const float *__restrict__ Wx,
                               const float *__restrict__ Wh,
                               const float *__restrict__ b,
                               float *__restrict__ hconst,
                               float *__restrict__ xw0) {
  const int k = blockIdx.x * 64 + threadIdx.x;
  if (k >= HID) return;
  double acc = 0.0;
  for (int j = 0; j < HID; ++j)
    acc = fma((double)hidden_init[j], (double)Wh[(size_t)j * HID + k], acc);
  hconst[k] = (float)(acc + (double)b[k]);
  double a2 = 0.0;
  for (int j = 0; j < 2 * VV; ++j)
    a2 = fma((double)input_init[j], (double)Wx[(size_t)j * HID + k], a2);
  xw0[k] = (float)a2;
}

// ---- H table: row r=(p+1)*65+(s+1) -> tanh of that (parent,sib) combo ----
// Bit-identical arithmetic to the in-sampler Phase A (f32 adds, f64 tanh).
__global__ void rnn_tanh_table(const float *__restrict__ Wx,
                               const float *__restrict__ hconst,
                               const float *__restrict__ xw0,
                               float *__restrict__ H) {
  const int r = blockIdx.x;
  const int k = threadIdx.x;
  float ax;
  if (r == H_T0) {
    ax = xw0[k];
  } else {
    const int p = r / 65 - 1;
    const int s = r % 65 - 1;
    ax = 0.f;
    if (p >= 0) ax = Wx[(size_t)p * HID + k];
    if (s >= 0) ax += Wx[(size_t)(VV + s) * HID + k];
  }
  H[(size_t)r * HID + k] = (float)tanh((double)(ax + hconst[k]));
}

// ---- gumbel table: g[t][idx], bit-identical RNG + f64 log chain ----
__global__ void rnn_gumbel_table(double *__restrict__ g) {
  const int t   = blockIdx.y;
  const int idx = blockIdx.x * blockDim.x + threadIdx.x;  // < NSEQ*VV
  uint32_t kt0, kt1;
  threefry2x32(0u, 1234u, 0u, (uint32_t)t, kt0, kt1);
  uint32_t b0, b1;
  threefry2x32(kt0, kt1, 0u, (uint32_t)idx, b0, b1);
  const uint32_t bits = b0 ^ b1;
  const float f = __uint_as_float((bits >> 9) | 0x3f800000u) - 1.0f;
  const double u = (f == 0.f) ? (double)1.17549435e-38f : (double)f;
  g[(size_t)t * (NSEQ * VV) + idx] = -log(-log(u));
}

// --------- main sampler: 8 waves = 8 seqs per block, Wp in registers -----
__global__ __launch_bounds__(NTHR) void rnn_sampler(
    const float *__restrict__ Wx, const float *__restrict__ Wp,
    const float *__restrict__ bp,
    const float *__restrict__ hconst_g, const float *__restrict__ xw0_g,
    const int *__restrict__ two_arr, int n2,
    const int *__restrict__ one_arr, int n1,
    const int *__restrict__ var_arr, int nv,
    const float *__restrict__ Htab, const double *__restrict__ gtab,
    int useH, int useG,
    float *__restrict__ out) {
  __shared__ float smh[SPB][HSTR];      // h per seq (f32)
  __shared__ float smp[SPB][SPB][VV];   // partial logits [kslice wave][seq][v]

  const int tid  = threadIdx.x;
  const int lane = tid & 63;
  const int w    = tid >> 6;
  const int n    = blockIdx.x * SPB + w;

  bool isTwo = false, isOne = false, isVar = false;
  for (int j = 0; j < n2; ++j) isTwo |= (lane == two_arr[j]);
  for (int j = 0; j < n1; ++j) isOne |= (lane == one_arr[j]);
  for (int j = 0; j < nv; ++j) isVar |= (lane == var_arr[j]);
  const unsigned long long two_mask = __ballot(isTwo);
  const unsigned long long one_mask = __ballot(isOne);
  const unsigned long long var_mask = __ballot(isVar);
  const bool two_v   = (two_mask >> lane) & 1ull;
  const bool one_v   = (one_mask >> lane) & 1ull;
  const bool zero_v  = !(two_v || one_v);
  const bool const_v = zero_v && !((var_mask >> lane) & 1ull);
  const float bp_v   = bp[lane];

  float hc[8], xw[8];
#pragma unroll
  for (int i = 0; i < 8; ++i) {
    hc[i] = hconst_g[i * 64 + lane];
    xw[i] = xw0_g[i * 64 + lane];
  }

  const int vg    = lane & 15;
  const int ksub  = lane >> 4;
  const int kbase = w * 64 + ksub * 16;

  float4 wpr[16];
#pragma unroll
  for (int kk = 0; kk < 16; ++kk)
    wpr[kk] = *(const float4 *)&Wp[(size_t)(kbase + kk) * VV + vg * 4];

  int myseq = -1;
  int counters = 1;
  bool alive = true, hasvar = false;
  double accE = 0.0, accLP = 0.0;
  int lenacc = 0;
  int parent = -1, sib = -1;

  for (int t = 0; t < LMAX; ++t) {
    // prefetch gumbel for this step (latency hidden under Phase A+B)
    double g_pre = 0.0;
    if (useG) g_pre = gtab[(size_t)t * (NSEQ * VV) + (n << 6) + lane];

    // ---- Phase A: h row for seq w (table lookup or compute)
    if (useH) {
      const int row = (t == 0) ? H_T0 : (parent + 1) * 65 + (sib + 1);
      const float *hr = Htab + (size_t)row * HID;
#pragma unroll
      for (int i = 0; i < 8; ++i) smh[w][i * 64 + lane] = hr[i * 64 + lane];
    } else {
#pragma unroll
      for (int i = 0; i < 8; ++i) {
        float ax;
        if (t == 0) {
          ax = xw[i];
        } else {
          ax = 0.f;
          if (parent >= 0) ax = Wx[(size_t)parent * HID + i * 64 + lane];
          if (sib >= 0) ax += Wx[(size_t)(VV + sib) * HID + i * 64 + lane];
        }
        smh[w][i * 64 + lane] = (float)tanh((double)(ax + hc[i]));
      }
    }
    __syncthreads();

    // ---- Phase B: partial logits for ALL 8 seqs, Wp from registers
    {
      float acc[SPB][4];
#pragma unroll
      for (int s = 0; s < SPB; ++s) {
        acc[s][0] = 0.f; acc[s][1] = 0.f; acc[s][2] = 0.f; acc[s][3] = 0.f;
      }
#pragma unroll
      for (int k4 = 0; k4 < 4; ++k4) {
#pragma unroll
        for (int s = 0; s < SPB; ++s) {
          float4 hv = *(const float4 *)&smh[s][kbase + k4 * 4];
          acc[s][0] = fmaf(hv.x, wpr[k4*4+0].x, acc[s][0]);
          acc[s][0] = fmaf(hv.y, wpr[k4*4+1].x, acc[s][0]);
          acc[s][0] = fmaf(hv.z, wpr[k4*4+2].x, acc[s][0]);
          acc[s][0] = fmaf(hv.w, wpr[k4*4+3].x, acc[s][0]);
          acc[s][1] = fmaf(hv.x, wpr[k4*4+0].y, acc[s][1]);
          acc[s][1] = fmaf(hv.y, wpr[k4*4+1].y, acc[s][1]);
          acc[s][1] = fmaf(hv.z, wpr[k4*4+2].y, acc[s][1]);
          acc[s][1] = fmaf(hv.w, wpr[k4*4+3].y, acc[s][1]);
          acc[s][2] = fmaf(hv.x, wpr[k4*4+0].z, acc[s][2]);
          acc[s][2] = fmaf(hv.y, wpr[k4*4+1].z, acc[s][2]);
          acc[s][2] = fmaf(hv.z, wpr[k4*4+2].z, acc[s][2]);
          acc[s][2] = fmaf(hv.w, wpr[k4*4+3].z, acc[s][2]);
          acc[s][3] = fmaf(hv.x, wpr[k4*4+0].w, acc[s][3]);
          acc[s][3] = fmaf(hv.y, wpr[k4*4+1].w, acc[s][3]);
          acc[s][3] = fmaf(hv.z, wpr[k4*4+2].w, acc[s][3]);
          acc[s][3] = fmaf(hv.w, wpr[k4*4+3].w, acc[s][3]);
        }
      }
#pragma unroll
      for (int s = 0; s < SPB; ++s) {
#pragma unroll
        for (int c = 0; c < 4; ++c) {
          acc[s][c] += __shfl_xor(acc[s][c], 16, 64);
          acc[s][c] += __shfl_xor(acc[s][c], 32, 64);
        }
      }
      if (ksub == 0) {
#pragma unroll
        for (int s = 0; s < SPB; ++s) {
          float4 v;
          v.x = acc[s][0]; v.y = acc[s][1]; v.z = acc[s][2]; v.w = acc[s][3];
          *(float4 *)&smp[w][s][vg * 4] = v;
        }
      }
    }
    __syncthreads();

    // ---- Phase C: softmax / mask / sample / state update (seq = w)
    {
      float lsum = 0.f;
#pragma unroll
      for (int ww = 0; ww < SPB; ++ww) lsum += smp[ww][w][lane];
      const float lraw = lsum + bp_v;

      const float mx = wmaxf64(lraw);
      const double e  = exp((double)(lraw - mx));
      const double S1 = dsum64(e);
      const double p1 = e / S1;

      const int tot = t + counters;
      bool keep = true;
      if (zero_v && tot < MINLEN) keep = false;
      if (two_v && (tot + 2 > LMAX)) keep = false;
      if (one_v && (tot + 1 > LMAX)) keep = false;
      if (const_v && !hasvar && (counters == 1)) keep = false;

      const double p  = keep ? p1 : 0.0;
      const double S2 = dsum64(p);
      const double p2 = p / fmax(S2, 1e-30);
      const bool   pos = p2 > 0.0;
      const double lg  = pos ? log(p2) : 0.0;
      const double lgi = pos ? lg : -__builtin_inf();

      double g;
      if (useG) {
        g = g_pre;
      } else {
        const uint32_t idx = (uint32_t)((n << 6) + lane);
        uint32_t kt0, kt1;
        threefry2x32(0u, 1234u, 0u, (uint32_t)t, kt0, kt1);
        uint32_t b0, b1;
        threefry2x32(kt0, kt1, 0u, idx, b0, b1);
        const uint32_t bits = b0 ^ b1;
        const float f = __uint_as_float((bits >> 9) | 0x3f800000u) - 1.0f;
        const double u = (f == 0.f) ? (double)1.17549435e-38f : (double)f;
        g = -log(-log(u));
      }

      const float val32 = (float)(g + lgi);

      float bv = val32; int bi = lane;
#pragma unroll
      for (int off = 32; off >= 1; off >>= 1) {
        float ov = __shfl_xor(bv, off, 64);
        int   oi = __shfl_xor(bi, off, 64);
        if (ov > bv || (ov == bv && oi < bi)) { bv = ov; bi = oi; }
      }
      const int token = bi;
      const double lp  = __shfl(lg, token, 64);
      const double ent = dsum64(pos ? (-p2 * lg) : 0.0);

      const bool tk2 = (two_mask >> token) & 1ull;
      const bool tk1 = (one_mask >> token) & 1ull;
      counters += -1 + 2 * (int)tk2 + (int)tk1;
      alive = alive && (counters > 0);
      if (alive) { accE += ent; accLP += lp; lenacc++; }
      hasvar = hasvar || ((var_mask >> token) & 1ull);

      if (lane == t) myseq = token;

      int a = 0;
      if (lane <= t) {
        const int tk = __shfl(myseq, t - lane, 64);
        a = -1 + 2 * (int)((two_mask >> tk) & 1ull) +
            (int)((one_mask >> tk) & 1ull);
      }
      int c = a;
#pragma unroll
      for (int off = 1; off < 64; off <<= 1) {
        int o = __shfl_up(c, off, 64);
        if (lane >= off) c += o;
      }
      const bool hit = (lane <= t) && (c == 0);
      const unsigned long long hb = __ballot(hit);
      if (tk2 || tk1) { parent = token; sib = -1; }
      else if (hb == 0ull) { parent = -1; sib = -1; }
      else {
        const int kf = __ffsll((long long)hb) - 1;
        parent = __shfl(myseq, t - kf, 64);
        sib = (kf == 0) ? -1 : __shfl(myseq, t - kf + 1, 64);
      }
    }
    __syncthreads();
  }

  out[(size_t)n * LMAX + lane] = (float)myseq;
  if (lane == 0) {
    out[(size_t)NSEQ * LMAX + n]       = (float)(lenacc + 1);
    out[(size_t)NSEQ * (LMAX + 1) + n] = (float)accE;
    out[(size_t)NSEQ * (LMAX + 2) + n] = (float)accLP;
  }
}

extern "C" void kernel_launch(void *const *d_in, const int *in_sizes, int n_in,
                              void *d_out, int out_size, void *d_ws, size_t ws_size,
                              hipStream_t stream) {
  (void)n_in; (void)out_size;
  const float *input_init  = (const float *)d_in[0];
  const float *hidden_init = (const float *)d_in[1];
  const float *Wx = (const float *)d_in[2];
  const float *Wh = (const float *)d_in[3];
  const float *b  = (const float *)d_in[4];
  const float *Wp = (const float *)d_in[5];
  const float *bp = (const float *)d_in[6];
  const int *two_arr = (const int *)d_in[7];
  const int *one_arr = (const int *)d_in[8];
  const int *var_arr = (const int *)d_in[9];
  const int n2 = in_sizes[7], n1 = in_sizes[8], nv = in_sizes[9];

  // workspace layout: [hconst 2KB | xw0 2KB | H 8.65MB | g 67.1MB]
  const size_t offH = 4096;
  const size_t szH  = (size_t)H_ROWS * HID * sizeof(float);
  const size_t offG = offH + szH;                    // 8,658,944 (8-aligned)
  const size_t szG  = (size_t)LMAX * NSEQ * VV * sizeof(double);
  const int useH = (ws_size >= offG) ? 1 : 0;
  const int useG = (ws_size >= offG + szG) ? 1 : 0;

  float  *hconst = (float *)d_ws;
  float  *xw0    = hconst + HID;
  float  *Htab   = (float *)((char *)d_ws + offH);
  double *gtab   = (double *)((char *)d_ws + offG);
  float  *out    = (float *)d_out;

  rnn_precompute<<<8, 64, 0, stream>>>(input_init, hidden_init, Wx, Wh, b,
                                       hconst, xw0);
  if (useH)
    rnn_tanh_table<<<H_ROWS, HID, 0, stream>>>(Wx, hconst, xw0, Htab);
  if (useG)
    rnn_gumbel_table<<<dim3((NSEQ * VV) / 256, LMAX), 256, 0, stream>>>(gtab);

  rnn_sampler<<<NSEQ / SPB, NTHR, 0, stream>>>(Wx, Wp, bp, hconst, xw0,
                                               two_arr, n2, one_arr, n1,
                                               var_arr, nv,
                                               Htab, gtab, useH, useG, out);
}

// Round 11
// 335.279 us; speedup vs baseline: 9.8857x; 1.4690x over previous
//
#include <hip/hip_runtime.h>
#include <stdint.h>
#include <math.h>

#define NSEQ   2048
#define VV     64
#define HID    512
#define LMAX   64
#define MINLEN 4
#define SPB    8      // sequences per block = waves per block
#define NTHR   512    // 8 waves
#define H_ROWS 4226   // 65*65 (parent,sib) rows + 1 row for t==0
#define H_T0   4225

// ---------------- threefry2x32 (JAX/Random123, 20 rounds; KAT-verified) ----
__device__ __forceinline__ uint32_t rotl32(uint32_t x, int r) {
  return (x << r) | (x >> (32 - r));
}
__device__ __forceinline__ void threefry2x32(uint32_t ks0, uint32_t ks1,
                                             uint32_t x0, uint32_t x1,
                                             uint32_t &o0, uint32_t &o1) {
  uint32_t ks2 = ks0 ^ ks1 ^ 0x1BD11BDAu;
  x0 += ks0; x1 += ks1;
#define TF_RND(r) { x0 += x1; x1 = rotl32(x1, (r)); x1 ^= x0; }
  TF_RND(13) TF_RND(15) TF_RND(26) TF_RND(6)
  x0 += ks1; x1 += ks2 + 1u;
  TF_RND(17) TF_RND(29) TF_RND(16) TF_RND(24)
  x0 += ks2; x1 += ks0 + 2u;
  TF_RND(13) TF_RND(15) TF_RND(26) TF_RND(6)
  x0 += ks0; x1 += ks1 + 3u;
  TF_RND(17) TF_RND(29) TF_RND(16) TF_RND(24)
  x0 += ks1; x1 += ks2 + 4u;
  TF_RND(13) TF_RND(15) TF_RND(26) TF_RND(6)
  x0 += ks2; x1 += ks0 + 5u;
#undef TF_RND
  o0 = x0; o1 = x1;
}

// ---- precompute (f64 accumulate, f32 store): hconst = h0@Wh + b ; xw0 ----
__global__ void rnn_precompute(const float *__restrict__ input_init,
                               const float *__restrict__ hidden_init,
                               const float *__restrict__ Wx,
                               const float *__restrict__ Wh,
                               const float *__restrict__ b,
                               float *__restrict__ hconst,
                               float *__restrict__ xw0) {
  const int k = blockIdx.x * 64 + threadIdx.x;
  if (k >= HID) return;
  double acc = 0.0;
  for (int j = 0; j < HID; ++j)
    acc = fma((double)hidden_init[j], (double)Wh[(size_t)j * HID + k], acc);
  hconst[k] = (float)(acc + (double)b[k]);
  double a2 = 0.0;
  for (int j = 0; j < 2 * VV; ++j)
    a2 = fma((double)input_init[j], (double)Wx[(size_t)j * HID + k], a2);
  xw0[k] = (float)a2;
}

// ---- H table: row r=(p+1)*65+(s+1) -> tanh of that (parent,sib) combo ----
__global__ void rnn_tanh_table(const float *__restrict__ Wx,
                               const float *__restrict__ hconst,
                               const float *__restrict__ xw0,
                               float *__restrict__ H) {
  const int r = blockIdx.x;
  const int k = threadIdx.x;
  float ax;
  if (r == H_T0) {
    ax = xw0[k];
  } else {
    const int p = r / 65 - 1;
    const int s = r % 65 - 1;
    ax = 0.f;
    if (p >= 0) ax = Wx[(size_t)p * HID + k];
    if (s >= 0) ax += Wx[(size_t)(VV + s) * HID + k];
  }
  H[(size_t)r * HID + k] = (float)tanh((double)(ax + hconst[k]));
}

// ---- gumbel table (f32): g[t][idx] = -logf(-logf(u)) ----
__global__ void rnn_gumbel_table(float *__restrict__ g) {
  const int t   = blockIdx.y;
  const int idx = blockIdx.x * blockDim.x + threadIdx.x;  // < NSEQ*VV
  uint32_t kt0, kt1;
  threefry2x32(0u, 1234u, 0u, (uint32_t)t, kt0, kt1);
  uint32_t b0, b1;
  threefry2x32(kt0, kt1, 0u, (uint32_t)idx, b0, b1);
  const uint32_t bits = b0 ^ b1;
  const float f = __uint_as_float((bits >> 9) | 0x3f800000u) - 1.0f;
  const float u = (f == 0.f) ? 1.17549435e-38f : f;
  g[(size_t)t * (NSEQ * VV) + idx] = -logf(-logf(u));
}

// --------- main sampler: 8 waves = 8 seqs per block, 2 barriers/step -----
__global__ __launch_bounds__(NTHR, 2) void rnn_sampler(
    const float *__restrict__ Wx, const float *__restrict__ Wp,
    const float *__restrict__ bp,
    const float *__restrict__ hconst_g, const float *__restrict__ xw0_g,
    const int *__restrict__ two_arr, int n2,
    const int *__restrict__ one_arr, int n1,
    const int *__restrict__ var_arr, int nv,
    const float *__restrict__ Htab, const float *__restrict__ gtab,
    int useH, int useG,
    float *__restrict__ out) {
  __shared__ float smp[SPB][4][SPB][VV];  // partials [wave][ksub][seq][v] 64KB
  __shared__ float smh[SPB][HID];         // fallback h staging (16KB)
  __shared__ int   smrow[SPB];            // current H-row per seq

  const int tid  = threadIdx.x;
  const int lane = tid & 63;              // = token id v
  const int w    = tid >> 6;              // wave id = local seq id
  const int n    = blockIdx.x * SPB + w;  // global sequence id

  // token-class bitmasks (lane == token id)
  bool isTwo = false, isOne = false, isVar = false;
  for (int j = 0; j < n2; ++j) isTwo |= (lane == two_arr[j]);
  for (int j = 0; j < n1; ++j) isOne |= (lane == one_arr[j]);
  for (int j = 0; j < nv; ++j) isVar |= (lane == var_arr[j]);
  const unsigned long long two_mask = __ballot(isTwo);
  const unsigned long long one_mask = __ballot(isOne);
  const unsigned long long var_mask = __ballot(isVar);
  const bool two_v   = (two_mask >> lane) & 1ull;
  const bool one_v   = (one_mask >> lane) & 1ull;
  const bool zero_v  = !(two_v || one_v);
  const bool const_v = zero_v && !((var_mask >> lane) & 1ull);
  const float bp_v   = bp[lane];

  // fallback-only per-lane slices
  float hc[8], xw[8];
#pragma unroll
  for (int i = 0; i < 8; ++i) {
    hc[i] = hconst_g[i * 64 + lane];
    xw[i] = xw0_g[i * 64 + lane];
  }

  // GEMM lane roles: wave w owns K-slice [64w,64w+64); lane = ksub(4)×vg(16)
  const int vg    = lane & 15;
  const int ksub  = lane >> 4;
  const int kbase = w * 64 + ksub * 16;

  float4 wpr[16];
#pragma unroll
  for (int kk = 0; kk < 16; ++kk)
    wpr[kk] = *(const float4 *)&Wp[(size_t)(kbase + kk) * VV + vg * 4];

  int rseq = -1;                 // lane L holds seq[t-L] (reversed history)
  int counters = 1;
  bool alive = true, hasvar = false;
  float accE = 0.f, accLP = 0.f;
  int lenacc = 0;

  if (tid < SPB) smrow[tid] = H_T0;
  __syncthreads();

  for (int t = 0; t < LMAX; ++t) {
    // gumbel for this step (table prefetch, hidden under Phase B)
    float g32;
    if (useG) {
      g32 = gtab[(size_t)t * (NSEQ * VV) + (n << 6) + lane];
    } else {
      uint32_t kt0, kt1, b0, b1;
      threefry2x32(0u, 1234u, 0u, (uint32_t)t, kt0, kt1);
      threefry2x32(kt0, kt1, 0u, (uint32_t)((n << 6) + lane), b0, b1);
      const uint32_t bits = b0 ^ b1;
      const float f = __uint_as_float((bits >> 9) | 0x3f800000u) - 1.0f;
      const float u = (f == 0.f) ? 1.17549435e-38f : f;
      g32 = -logf(-logf(u));
    }

    // ---- fallback Phase A (only when Htab absent): stage h in LDS
    if (!useH) {
      const int row = smrow[w];
#pragma unroll
      for (int i = 0; i < 8; ++i) {
        float ax;
        if (row == H_T0) {
          ax = xw[i];
        } else {
          const int p  = row / 65 - 1;
          const int sb = row % 65 - 1;
          ax = 0.f;
          if (p >= 0) ax = Wx[(size_t)p * HID + i * 64 + lane];
          if (sb >= 0) ax += Wx[(size_t)(VV + sb) * HID + i * 64 + lane];
        }
        smh[w][i * 64 + lane] = (float)tanh((double)(ax + hc[i]));
      }
      __syncthreads();
    }

    // ---- Phase B: partial logits for ALL 8 seqs (h direct from L2 table)
    {
      float acc[SPB][4];
#pragma unroll
      for (int s = 0; s < SPB; ++s) {
        acc[s][0] = 0.f; acc[s][1] = 0.f; acc[s][2] = 0.f; acc[s][3] = 0.f;
      }
#pragma unroll
      for (int s = 0; s < SPB; ++s) {
        const float *hb_ = useH ? (Htab + (size_t)smrow[s] * HID + kbase)
                                : (&smh[s][kbase]);
#pragma unroll
        for (int k4 = 0; k4 < 4; ++k4) {
          float4 hv = *(const float4 *)&hb_[k4 * 4];
          acc[s][0] = fmaf(hv.x, wpr[k4*4+0].x, acc[s][0]);
          acc[s][0] = fmaf(hv.y, wpr[k4*4+1].x, acc[s][0]);
          acc[s][0] = fmaf(hv.z, wpr[k4*4+2].x, acc[s][0]);
          acc[s][0] = fmaf(hv.w, wpr[k4*4+3].x, acc[s][0]);
          acc[s][1] = fmaf(hv.x, wpr[k4*4+0].y, acc[s][1]);
          acc[s][1] = fmaf(hv.y, wpr[k4*4+1].y, acc[s][1]);
          acc[s][1] = fmaf(hv.z, wpr[k4*4+2].y, acc[s][1]);
          acc[s][1] = fmaf(hv.w, wpr[k4*4+3].y, acc[s][1]);
          acc[s][2] = fmaf(hv.x, wpr[k4*4+0].z, acc[s][2]);
          acc[s][2] = fmaf(hv.y, wpr[k4*4+1].z, acc[s][2]);
          acc[s][2] = fmaf(hv.z, wpr[k4*4+2].z, acc[s][2]);
          acc[s][2] = fmaf(hv.w, wpr[k4*4+3].z, acc[s][2]);
          acc[s][3] = fmaf(hv.x, wpr[k4*4+0].w, acc[s][3]);
          acc[s][3] = fmaf(hv.y, wpr[k4*4+1].w, acc[s][3]);
          acc[s][3] = fmaf(hv.z, wpr[k4*4+2].w, acc[s][3]);
          acc[s][3] = fmaf(hv.w, wpr[k4*4+3].w, acc[s][3]);
        }
      }
      // write unreduced partials (C sums them — no shuffle reduce)
#pragma unroll
      for (int s = 0; s < SPB; ++s) {
        float4 v;
        v.x = acc[s][0]; v.y = acc[s][1]; v.z = acc[s][2]; v.w = acc[s][3];
        *(float4 *)&smp[w][ksub][s][vg * 4] = v;
      }
    }
    __syncthreads();

    // ---- Phase C: decide token, update state (seq = w)
    {
      float x = bp_v;
#pragma unroll
      for (int ww = 0; ww < SPB; ++ww)
#pragma unroll
        for (int ks = 0; ks < 4; ++ks)
          x += smp[ww][ks][w][lane];

      const int tot = t + counters;
      bool keep = true;
      if (zero_v && tot < MINLEN) keep = false;
      if (two_v && (tot + 2 > LMAX)) keep = false;
      if (one_v && (tot + 1 > LMAX)) keep = false;
      if (const_v && !hasvar && (counters == 1)) keep = false;

      const float e  = expf(x);
      const float ek = keep ? e : 0.f;
      float val = keep ? (g32 + x) : -__builtin_inff();

      // fused butterfly: S2 sum, dot sum, max — 3 interleaved chains
      float s2 = ek, dd = ek * x, mv = val;
#pragma unroll
      for (int off = 32; off >= 1; off >>= 1) {
        s2 += __shfl_xor(s2, off, 64);
        dd += __shfl_xor(dd, off, 64);
        mv = fmaxf(mv, __shfl_xor(mv, off, 64));
      }
      const unsigned long long win = __ballot(val == mv);
      const int token = __ffsll((long long)win) - 1;

      const bool tk2 = (two_mask >> token) & 1ull;
      const bool tk1 = (one_mask >> token) & 1ull;
      const bool tkv = (var_mask >> token) & 1ull;

      // reversed-history shift: rseq[lane] = seq[t-lane]
      const int up = __shfl_up(rseq, 1, 64);
      rseq = (lane == 0) ? token : up;

      // parent/sibling via ballot+popcount (DS-free prefix sum)
      const bool vld = lane <= t;
      const int tkl = rseq & 63;
      const unsigned long long twoB =
          __ballot(vld && ((two_mask >> tkl) & 1ull));
      const unsigned long long oneB =
          __ballot(vld && ((one_mask >> tkl) & 1ull));
      const unsigned long long mle = (2ull << lane) - 1ull; // lane63 -> ~0
      const int c = 2 * __popcll(twoB & mle) + __popcll(oneB & mle) -
                    (lane + 1);
      const unsigned long long hb = __ballot(vld && (c == 0));

      int parent, sib;
      if (tk2 || tk1) { parent = token; sib = -1; }
      else if (hb == 0ull) { parent = -1; sib = -1; }
      else {
        int kf = __ffsll((long long)hb) - 1;
        kf = __builtin_amdgcn_readfirstlane(kf);
        parent = __builtin_amdgcn_readlane(rseq, kf);
        sib = (kf == 0) ? -1 : __builtin_amdgcn_readlane(rseq, kf - 1);
      }
      if (lane == 0) smrow[w] = (parent + 1) * 65 + (sib + 1);

      // stats (loose tolerance): lp = x_tok - logS2 ; ent = logS2 - dot/S2
      const float logS2 = logf(s2);
      const int tok_u = __builtin_amdgcn_readfirstlane(token);
      const float x_tok = __int_as_float(
          __builtin_amdgcn_readlane(__float_as_int(x), tok_u));
      const float lp  = x_tok - logS2;
      const float ent = logS2 - dd / s2;

      counters += -1 + 2 * (int)tk2 + (int)tk1;
      alive = alive && (counters > 0);
      if (alive) { accE += ent; accLP += lp; lenacc++; }
      hasvar = hasvar || tkv;
    }
    __syncthreads();
  }

  // ---- outputs (f32): [seq (2048x64) | lengths | ents | lps]
  out[(size_t)n * LMAX + (63 - lane)] = (float)rseq;  // un-reverse
  if (lane == 0) {
    out[(size_t)NSEQ * LMAX + n]       = (float)(lenacc + 1);
    out[(size_t)NSEQ * (LMAX + 1) + n] = accE;
    out[(size_t)NSEQ * (LMAX + 2) + n] = accLP;
  }
}

extern "C" void kernel_launch(void *const *d_in, const int *in_sizes, int n_in,
                              void *d_out, int out_size, void *d_ws, size_t ws_size,
                              hipStream_t stream) {
  (void)n_in; (void)out_size;
  const float *input_init  = (const float *)d_in[0];
  const float *hidden_init = (const float *)d_in[1];
  const float *Wx = (const float *)d_in[2];
  const float *Wh = (const float *)d_in[3];
  const float *b  = (const float *)d_in[4];
  const float *Wp = (const float *)d_in[5];
  const float *bp = (const float *)d_in[6];
  const int *two_arr = (const int *)d_in[7];
  const int *one_arr = (const int *)d_in[8];
  const int *var_arr = (const int *)d_in[9];
  const int n2 = in_sizes[7], n1 = in_sizes[8], nv = in_sizes[9];

  // workspace layout: [hconst 2KB | xw0 2KB | H 8.65MB | g(f32) 33.5MB]
  const size_t offH = 4096;
  const size_t szH  = (size_t)H_ROWS * HID * sizeof(float);
  const size_t offG = offH + szH;
  const size_t szG  = (size_t)LMAX * NSEQ * VV * sizeof(float);
  const int useH = (ws_size >= offG) ? 1 : 0;
  const int useG = (ws_size >= offG + szG) ? 1 : 0;

  float *hconst = (float *)d_ws;
  float *xw0    = hconst + HID;
  float *Htab   = (float *)((char *)d_ws + offH);
  float *gtab   = (float *)((char *)d_ws + offG);
  float *out    = (float *)d_out;

  rnn_precompute<<<8, 64, 0, stream>>>(input_init, hidden_init, Wx, Wh, b,
                                       hconst, xw0);
  if (useH)
    rnn_tanh_table<<<H_ROWS, HID, 0, stream>>>(Wx, hconst, xw0, Htab);
  if (useG)
    rnn_gumbel_table<<<dim3((NSEQ * VV) / 256, LMAX), 256, 0, stream>>>(gtab);

  rnn_sampler<<<NSEQ / SPB, NTHR, 0, stream>>>(Wx, Wp, bp, hconst, xw0,
                                               two_arr, n2, one_arr, n1,
                                               var_arr, nv,
                                               Htab, gtab, useH, useG, out);
}

// Round 12
// 335.201 us; speedup vs baseline: 9.8880x; 1.0002x over previous
//
#include <hip/hip_runtime.h>
#include <stdint.h>
#include <math.h>

#define NSEQ   2048
#define VV     64
#define HID    512
#define LMAX   64
#define MINLEN 4
#define SPB    8      // sequences per block = waves per block
#define NTHR   512    // 8 waves
#define H_ROWS 4226   // 65*65 (parent,sib) rows + 1 row for t==0
#define H_T0   4225

// ---------------- threefry2x32 (JAX/Random123, 20 rounds; KAT-verified) ----
__device__ __forceinline__ uint32_t rotl32(uint32_t x, int r) {
  return (x << r) | (x >> (32 - r));
}
__device__ __forceinline__ void threefry2x32(uint32_t ks0, uint32_t ks1,
                                             uint32_t x0, uint32_t x1,
                                             uint32_t &o0, uint32_t &o1) {
  uint32_t ks2 = ks0 ^ ks1 ^ 0x1BD11BDAu;
  x0 += ks0; x1 += ks1;
#define TF_RND(r) { x0 += x1; x1 = rotl32(x1, (r)); x1 ^= x0; }
  TF_RND(13) TF_RND(15) TF_RND(26) TF_RND(6)
  x0 += ks1; x1 += ks2 + 1u;
  TF_RND(17) TF_RND(29) TF_RND(16) TF_RND(24)
  x0 += ks2; x1 += ks0 + 2u;
  TF_RND(13) TF_RND(15) TF_RND(26) TF_RND(6)
  x0 += ks0; x1 += ks1 + 3u;
  TF_RND(17) TF_RND(29) TF_RND(16) TF_RND(24)
  x0 += ks1; x1 += ks2 + 4u;
  TF_RND(13) TF_RND(15) TF_RND(26) TF_RND(6)
  x0 += ks2; x1 += ks0 + 5u;
#undef TF_RND
  o0 = x0; o1 = x1;
}

// ---- precompute (f64 accumulate, f32 store): hconst = h0@Wh + b ; xw0 ----
__global__ void rnn_precompute(const float *__restrict__ input_init,
                               const float *__restrict__ hidden_init,
                               const float *__restrict__ Wx,
                               const float *__restrict__ Wh,
                               const float *__restrict__ b,
                               float *__restrict__ hconst,
                               float *__restrict__ xw0) {
  const int k = blockIdx.x * 64 + threadIdx.x;
  if (k >= HID) return;
  double acc = 0.0;
  for (int j = 0; j < HID; ++j)
    acc = fma((double)hidden_init[j], (double)Wh[(size_t)j * HID + k], acc);
  hconst[k] = (float)(acc + (double)b[k]);
  double a2 = 0.0;
  for (int j = 0; j < 2 * VV; ++j)
    a2 = fma((double)input_init[j], (double)Wx[(size_t)j * HID + k], a2);
  xw0[k] = (float)a2;
}

// ---- H table: row r=(p+1)*65+(s+1) -> tanh of that (parent,sib) combo ----
__global__ void rnn_tanh_table(const float *__restrict__ Wx,
                               const float *__restrict__ hconst,
                               const float *__restrict__ xw0,
                               float *__restrict__ H) {
  const int r = blockIdx.x;
  const int k = threadIdx.x;
  float ax;
  if (r == H_T0) {
    ax = xw0[k];
  } else {
    const int p = r / 65 - 1;
    const int s = r % 65 - 1;
    ax = 0.f;
    if (p >= 0) ax = Wx[(size_t)p * HID + k];
    if (s >= 0) ax += Wx[(size_t)(VV + s) * HID + k];
  }
  H[(size_t)r * HID + k] = (float)tanh((double)(ax + hconst[k]));
}

// ---- gumbel table (f32): g[t][idx] = -logf(-logf(u)) ----
__global__ void rnn_gumbel_table(float *__restrict__ g) {
  const int t   = blockIdx.y;
  const int idx = blockIdx.x * blockDim.x + threadIdx.x;  // < NSEQ*VV
  uint32_t kt0, kt1;
  threefry2x32(0u, 1234u, 0u, (uint32_t)t, kt0, kt1);
  uint32_t b0, b1;
  threefry2x32(kt0, kt1, 0u, (uint32_t)idx, b0, b1);
  const uint32_t bits = b0 ^ b1;
  const float f = __uint_as_float((bits >> 9) | 0x3f800000u) - 1.0f;
  const float u = (f == 0.f) ? 1.17549435e-38f : f;
  g[(size_t)t * (NSEQ * VV) + idx] = -logf(-logf(u));
}

// --------- main sampler: 8 waves = 8 seqs per block, 2 barriers/step -----
__global__ __launch_bounds__(NTHR, 2) void rnn_sampler(
    const float *__restrict__ Wx, const float *__restrict__ Wp,
    const float *__restrict__ bp,
    const float *__restrict__ hconst_g, const float *__restrict__ xw0_g,
    const int *__restrict__ two_arr, int n2,
    const int *__restrict__ one_arr, int n1,
    const int *__restrict__ var_arr, int nv,
    const float *__restrict__ Htab, const float *__restrict__ gtab,
    int useH, int useG,
    float *__restrict__ out) {
  __shared__ float smp[SPB][4][SPB][VV];  // partials [wave][ksub][seq][v] 64KB
  __shared__ float smh[SPB][HID];         // fallback h staging (16KB)
  __shared__ int   smrow[SPB];            // current H-row per seq

  const int tid  = threadIdx.x;
  const int lane = tid & 63;              // = token id v
  const int w    = tid >> 6;              // wave id = local seq id
  const int n    = blockIdx.x * SPB + w;  // global sequence id

  // token-class bitmasks (lane == token id)
  bool isTwo = false, isOne = false, isVar = false;
  for (int j = 0; j < n2; ++j) isTwo |= (lane == two_arr[j]);
  for (int j = 0; j < n1; ++j) isOne |= (lane == one_arr[j]);
  for (int j = 0; j < nv; ++j) isVar |= (lane == var_arr[j]);
  const unsigned long long two_mask = __ballot(isTwo);
  const unsigned long long one_mask = __ballot(isOne);
  const unsigned long long var_mask = __ballot(isVar);
  const bool two_v   = (two_mask >> lane) & 1ull;
  const bool one_v   = (one_mask >> lane) & 1ull;
  const bool zero_v  = !(two_v || one_v);
  const bool const_v = zero_v && !((var_mask >> lane) & 1ull);
  const float bp_v   = bp[lane];

  // fallback-only per-lane slices
  float hc[8], xw[8];
#pragma unroll
  for (int i = 0; i < 8; ++i) {
    hc[i] = hconst_g[i * 64 + lane];
    xw[i] = xw0_g[i * 64 + lane];
  }

  // GEMM lane roles: wave w owns K-slice [64w,64w+64); lane = ksub(4)×vg(16)
  const int vg    = lane & 15;
  const int ksub  = lane >> 4;
  const int kbase = w * 64 + ksub * 16;

  float4 wpr[16];
#pragma unroll
  for (int kk = 0; kk < 16; ++kk)
    wpr[kk] = *(const float4 *)&Wp[(size_t)(kbase + kk) * VV + vg * 4];

  int rseq = -1;                 // lane L holds seq[t-L] (reversed history)
  int counters = 1;
  bool alive = true, hasvar = false;
  float accE = 0.f, accLP = 0.f;
  int lenacc = 0;

  if (tid < SPB) smrow[tid] = H_T0;
  __syncthreads();

  for (int t = 0; t < LMAX; ++t) {
    // gumbel for this step (table prefetch, hidden under Phase B)
    float g32;
    if (useG) {
      g32 = gtab[(size_t)t * (NSEQ * VV) + (n << 6) + lane];
    } else {
      uint32_t kt0, kt1, b0, b1;
      threefry2x32(0u, 1234u, 0u, (uint32_t)t, kt0, kt1);
      threefry2x32(kt0, kt1, 0u, (uint32_t)((n << 6) + lane), b0, b1);
      const uint32_t bits = b0 ^ b1;
      const float f = __uint_as_float((bits >> 9) | 0x3f800000u) - 1.0f;
      const float u = (f == 0.f) ? 1.17549435e-38f : f;
      g32 = -logf(-logf(u));
    }

    // ---- fallback Phase A (only when Htab absent): stage h in LDS
    if (!useH) {
      const int row = smrow[w];
#pragma unroll
      for (int i = 0; i < 8; ++i) {
        float ax;
        if (row == H_T0) {
          ax = xw[i];
        } else {
          const int p  = row / 65 - 1;
          const int sb = row % 65 - 1;
          ax = 0.f;
          if (p >= 0) ax = Wx[(size_t)p * HID + i * 64 + lane];
          if (sb >= 0) ax += Wx[(size_t)(VV + sb) * HID + i * 64 + lane];
        }
        smh[w][i * 64 + lane] = (float)tanh((double)(ax + hc[i]));
      }
      __syncthreads();
    }

    // ---- Phase B: partial logits for ALL 8 seqs (h direct from L2 table)
    {
      float acc[SPB][4];
#pragma unroll
      for (int s = 0; s < SPB; ++s) {
        acc[s][0] = 0.f; acc[s][1] = 0.f; acc[s][2] = 0.f; acc[s][3] = 0.f;
      }
#pragma unroll
      for (int s = 0; s < SPB; ++s) {
        const float *hb_ = useH ? (Htab + (size_t)smrow[s] * HID + kbase)
                                : (&smh[s][kbase]);
#pragma unroll
        for (int k4 = 0; k4 < 4; ++k4) {
          float4 hv = *(const float4 *)&hb_[k4 * 4];
          acc[s][0] = fmaf(hv.x, wpr[k4*4+0].x, acc[s][0]);
          acc[s][0] = fmaf(hv.y, wpr[k4*4+1].x, acc[s][0]);
          acc[s][0] = fmaf(hv.z, wpr[k4*4+2].x, acc[s][0]);
          acc[s][0] = fmaf(hv.w, wpr[k4*4+3].x, acc[s][0]);
          acc[s][1] = fmaf(hv.x, wpr[k4*4+0].y, acc[s][1]);
          acc[s][1] = fmaf(hv.y, wpr[k4*4+1].y, acc[s][1]);
          acc[s][1] = fmaf(hv.z, wpr[k4*4+2].y, acc[s][1]);
          acc[s][1] = fmaf(hv.w, wpr[k4*4+3].y, acc[s][1]);
          acc[s][2] = fmaf(hv.x, wpr[k4*4+0].z, acc[s][2]);
          acc[s][2] = fmaf(hv.y, wpr[k4*4+1].z, acc[s][2]);
          acc[s][2] = fmaf(hv.z, wpr[k4*4+2].z, acc[s][2]);
          acc[s][2] = fmaf(hv.w, wpr[k4*4+3].z, acc[s][2]);
          acc[s][3] = fmaf(hv.x, wpr[k4*4+0].w, acc[s][3]);
          acc[s][3] = fmaf(hv.y, wpr[k4*4+1].w, acc[s][3]);
          acc[s][3] = fmaf(hv.z, wpr[k4*4+2].w, acc[s][3]);
          acc[s][3] = fmaf(hv.w, wpr[k4*4+3].w, acc[s][3]);
        }
      }
      // write unreduced partials (C sums them — no shuffle reduce)
#pragma unroll
      for (int s = 0; s < SPB; ++s) {
        float4 v;
        v.x = acc[s][0]; v.y = acc[s][1]; v.z = acc[s][2]; v.w = acc[s][3];
        *(float4 *)&smp[w][ksub][s][vg * 4] = v;
      }
    }
    __syncthreads();

    // ---- Phase C: decide token, update state (seq = w)
    {
      float x = bp_v;
#pragma unroll
      for (int ww = 0; ww < SPB; ++ww)
#pragma unroll
        for (int ks = 0; ks < 4; ++ks)
          x += smp[ww][ks][w][lane];

      const int tot = t + counters;
      bool keep = true;
      if (zero_v && tot < MINLEN) keep = false;
      if (two_v && (tot + 2 > LMAX)) keep = false;
      if (one_v && (tot + 1 > LMAX)) keep = false;
      if (const_v && !hasvar && (counters == 1)) keep = false;

      const float e  = expf(x);
      const float ek = keep ? e : 0.f;
      float val = keep ? (g32 + x) : -__builtin_inff();

      // fused butterfly: S2 sum, dot sum, max — 3 interleaved chains
      float s2 = ek, dd = ek * x, mv = val;
#pragma unroll
      for (int off = 32; off >= 1; off >>= 1) {
        s2 += __shfl_xor(s2, off, 64);
        dd += __shfl_xor(dd, off, 64);
        mv = fmaxf(mv, __shfl_xor(mv, off, 64));
      }
      const unsigned long long win = __ballot(val == mv);
      const int token = __ffsll((long long)win) - 1;

      const bool tk2 = (two_mask >> token) & 1ull;
      const bool tk1 = (one_mask >> token) & 1ull;
      const bool tkv = (var_mask >> token) & 1ull;

      // reversed-history shift: rseq[lane] = seq[t-lane]
      const int up = __shfl_up(rseq, 1, 64);
      rseq = (lane == 0) ? token : up;

      // parent/sibling via ballot+popcount (DS-free prefix sum)
      const bool vld = lane <= t;
      const int tkl = rseq & 63;
      const unsigned long long twoB =
          __ballot(vld && ((two_mask >> tkl) & 1ull));
      const unsigned long long oneB =
          __ballot(vld && ((one_mask >> tkl) & 1ull));
      const unsigned long long mle = (2ull << lane) - 1ull; // lane63 -> ~0
      const int c = 2 * __popcll(twoB & mle) + __popcll(oneB & mle) -
                    (lane + 1);
      const unsigned long long hb = __ballot(vld && (c == 0));

      int parent, sib;
      if (tk2 || tk1) { parent = token; sib = -1; }
      else if (hb == 0ull) { parent = -1; sib = -1; }
      else {
        int kf = __ffsll((long long)hb) - 1;
        kf = __builtin_amdgcn_readfirstlane(kf);
        parent = __builtin_amdgcn_readlane(rseq, kf);
        sib = (kf == 0) ? -1 : __builtin_amdgcn_readlane(rseq, kf - 1);
      }
      if (lane == 0) smrow[w] = (parent + 1) * 65 + (sib + 1);

      // stats (loose tolerance): lp = x_tok - logS2 ; ent = logS2 - dot/S2
      const float logS2 = logf(s2);
      const int tok_u = __builtin_amdgcn_readfirstlane(token);
      const float x_tok = __int_as_float(
          __builtin_amdgcn_readlane(__float_as_int(x), tok_u));
      const float lp  = x_tok - logS2;
      const float ent = logS2 - dd / s2;

      counters += -1 + 2 * (int)tk2 + (int)tk1;
      alive = alive && (counters > 0);
      if (alive) { accE += ent; accLP += lp; lenacc++; }
      hasvar = hasvar || tkv;
    }
    __syncthreads();
  }

  // ---- outputs (f32): [seq (2048x64) | lengths | ents | lps]
  out[(size_t)n * LMAX + (63 - lane)] = (float)rseq;  // un-reverse
  if (lane == 0) {
    out[(size_t)NSEQ * LMAX + n]       = (float)(lenacc + 1);
    out[(size_t)NSEQ * (LMAX + 1) + n] = accE;
    out[(size_t)NSEQ * (LMAX + 2) + n] = accLP;
  }
}

extern "C" void kernel_launch(void *const *d_in, const int *in_sizes, int n_in,
                              void *d_out, int out_size, void *d_ws, size_t ws_size,
                              hipStream_t stream) {
  (void)n_in; (void)out_size;
  const float *input_init  = (const float *)d_in[0];
  const float *hidden_init = (const float *)d_in[1];
  const float *Wx = (const float *)d_in[2];
  const float *Wh = (const float *)d_in[3];
  const float *b  = (const float *)d_in[4];
  const float *Wp = (const float *)d_in[5];
  const float *bp = (const float *)d_in[6];
  const int *two_arr = (const int *)d_in[7];
  const int *one_arr = (const int *)d_in[8];
  const int *var_arr = (const int *)d_in[9];
  const int n2 = in_sizes[7], n1 = in_sizes[8], nv = in_sizes[9];

  // workspace layout: [hconst 2KB | xw0 2KB | H 8.65MB | g(f32) 33.5MB]
  const size_t offH = 4096;
  const size_t szH  = (size_t)H_ROWS * HID * sizeof(float);
  const size_t offG = offH + szH;
  const size_t szG  = (size_t)LMAX * NSEQ * VV * sizeof(float);
  const int useH = (ws_size >= offG) ? 1 : 0;
  const int useG = (ws_size >= offG + szG) ? 1 : 0;

  float *hconst = (float *)d_ws;
  float *xw0    = hconst + HID;
  float *Htab   = (float *)((char *)d_ws + offH);
  float *gtab   = (float *)((char *)d_ws + offG);
  float *out    = (float *)d_out;

  rnn_precompute<<<8, 64, 0, stream>>>(input_init, hidden_init, Wx, Wh, b,
                                       hconst, xw0);
  if (useH)
    rnn_tanh_table<<<H_ROWS, HID, 0, stream>>>(Wx, hconst, xw0, Htab);
  if (useG)
    rnn_gumbel_table<<<dim3((NSEQ * VV) / 256, LMAX), 256, 0, stream>>>(gtab);

  rnn_sampler<<<NSEQ / SPB, NTHR, 0, stream>>>(Wx, Wp, bp, hconst, xw0,
                                               two_arr, n2, one_arr, n1,
                                               var_arr, nv,
                                               Htab, gtab, useH, useG, out);
}

// Round 13
// 166.408 us; speedup vs baseline: 19.9176x; 2.0143x over previous
//
#include <hip/hip_runtime.h>
#include <stdint.h>
#include <math.h>

#define NSEQ   2048
#define VV     64
#define HID    512
#define LMAX   64
#define MINLEN 4
#define H_ROWS 4226   // 65*65 (parent,sib) rows + 1 row for t==0
#define H_T0   4225

// ---------------- threefry2x32 (JAX/Random123, 20 rounds; KAT-verified) ----
__device__ __forceinline__ uint32_t rotl32(uint32_t x, int r) {
  return (x << r) | (x >> (32 - r));
}
__device__ __forceinline__ void threefry2x32(uint32_t ks0, uint32_t ks1,
                                             uint32_t x0, uint32_t x1,
                                             uint32_t &o0, uint32_t &o1) {
  uint32_t ks2 = ks0 ^ ks1 ^ 0x1BD11BDAu;
  x0 += ks0; x1 += ks1;
#define TF_RND(r) { x0 += x1; x1 = rotl32(x1, (r)); x1 ^= x0; }
  TF_RND(13) TF_RND(15) TF_RND(26) TF_RND(6)
  x0 += ks1; x1 += ks2 + 1u;
  TF_RND(17) TF_RND(29) TF_RND(16) TF_RND(24)
  x0 += ks2; x1 += ks0 + 2u;
  TF_RND(13) TF_RND(15) TF_RND(26) TF_RND(6)
  x0 += ks0; x1 += ks1 + 3u;
  TF_RND(17) TF_RND(29) TF_RND(16) TF_RND(24)
  x0 += ks1; x1 += ks2 + 4u;
  TF_RND(13) TF_RND(15) TF_RND(26) TF_RND(6)
  x0 += ks2; x1 += ks0 + 5u;
#undef TF_RND
  o0 = x0; o1 = x1;
}

// ---- precompute (f64 accumulate, f32 store): hconst = h0@Wh + b ; xw0 ----
__global__ void rnn_precompute(const float *__restrict__ input_init,
                               const float *__restrict__ hidden_init,
                               const float *__restrict__ Wx,
                               const float *__restrict__ Wh,
                               const float *__restrict__ b,
                               float *__restrict__ hconst,
                               float *__restrict__ xw0) {
  const int k = blockIdx.x * 64 + threadIdx.x;
  if (k >= HID) return;
  double acc = 0.0;
  for (int j = 0; j < HID; ++j)
    acc = fma((double)hidden_init[j], (double)Wh[(size_t)j * HID + k], acc);
  hconst[k] = (float)(acc + (double)b[k]);
  double a2 = 0.0;
  for (int j = 0; j < 2 * VV; ++j)
    a2 = fma((double)input_init[j], (double)Wx[(size_t)j * HID + k], a2);
  xw0[k] = (float)a2;
}

// ---- X table: row r -> full logits vector x[v] = H[r]·Wp[:,v] + bp[v] ----
// h computed bit-identically to prior rounds (f32 adds, f64 tanh);
// dot accumulated in f64 (≈exact), rounded once to f32.
__global__ __launch_bounds__(512) void rnn_xtable(
    const float *__restrict__ Wx, const float *__restrict__ Wp,
    const float *__restrict__ bp,
    const float *__restrict__ hconst, const float *__restrict__ xw0,
    float *__restrict__ X) {
  __shared__ double smh[HID];
  __shared__ double smpart[8][VV];

  const int r   = blockIdx.x;
  const int tid = threadIdx.x;

  // h for this row
  {
    float ax;
    if (r == H_T0) {
      ax = xw0[tid];
    } else {
      const int p = r / 65 - 1;
      const int s = r % 65 - 1;
      ax = 0.f;
      if (p >= 0) ax = Wx[(size_t)p * HID + tid];
      if (s >= 0) ax += Wx[(size_t)(VV + s) * HID + tid];
    }
    smh[tid] = tanh((double)(ax + hconst[tid]));
  }
  __syncthreads();

  // 8 slices × 64 outputs
  const int v  = tid & 63;
  const int sl = tid >> 6;
  double acc = 0.0;
  for (int k = sl * 64; k < sl * 64 + 64; ++k)
    acc = fma(smh[k], (double)Wp[(size_t)k * VV + v], acc);
  smpart[sl][v] = acc;
  __syncthreads();

  if (tid < VV) {
    double s = 0.0;
#pragma unroll
    for (int i = 0; i < 8; ++i) s += smpart[i][tid];
    X[(size_t)r * VV + tid] = (float)(s + (double)bp[tid]);
  }
}

// ---- gumbel table (f32): g[t][idx] = -logf(-logf(u)) ----
__global__ void rnn_gumbel_table(float *__restrict__ g) {
  const int t   = blockIdx.y;
  const int idx = blockIdx.x * blockDim.x + threadIdx.x;  // < NSEQ*VV
  uint32_t kt0, kt1;
  threefry2x32(0u, 1234u, 0u, (uint32_t)t, kt0, kt1);
  uint32_t b0, b1;
  threefry2x32(kt0, kt1, 0u, (uint32_t)idx, b0, b1);
  const uint32_t bits = b0 ^ b1;
  const float f = __uint_as_float((bits >> 9) | 0x3f800000u) - 1.0f;
  const float u = (f == 0.f) ? 1.17549435e-38f : f;
  g[(size_t)t * (NSEQ * VV) + idx] = -logf(-logf(u));
}

// --------- main sampler: 1 wave = 1 seq, no LDS, no barriers -----
__global__ __launch_bounds__(64) void rnn_sampler(
    const float *__restrict__ Wx, const float *__restrict__ Wp,
    const float *__restrict__ bp,
    const float *__restrict__ hconst_g, const float *__restrict__ xw0_g,
    const int *__restrict__ two_arr, int n2,
    const int *__restrict__ one_arr, int n1,
    const int *__restrict__ var_arr, int nv,
    const float *__restrict__ Xtab, const float *__restrict__ gtab,
    int useX, int useG,
    float *__restrict__ out) {
  const int lane = threadIdx.x;   // = token id v
  const int n    = blockIdx.x;    // sequence id

  bool isTwo = false, isOne = false, isVar = false;
  for (int j = 0; j < n2; ++j) isTwo |= (lane == two_arr[j]);
  for (int j = 0; j < n1; ++j) isOne |= (lane == one_arr[j]);
  for (int j = 0; j < nv; ++j) isVar |= (lane == var_arr[j]);
  const unsigned long long two_mask = __ballot(isTwo);
  const unsigned long long one_mask = __ballot(isOne);
  const unsigned long long var_mask = __ballot(isVar);
  const bool two_v   = (two_mask >> lane) & 1ull;
  const bool one_v   = (one_mask >> lane) & 1ull;
  const bool zero_v  = !(two_v || one_v);
  const bool const_v = zero_v && !((var_mask >> lane) & 1ull);
  const float bp_v   = bp[lane];

  // fallback-only per-lane slices (k = 64*i + lane)
  float hc[8], xw[8];
  if (!useX) {
#pragma unroll
    for (int i = 0; i < 8; ++i) {
      hc[i] = hconst_g[i * 64 + lane];
      xw[i] = xw0_g[i * 64 + lane];
    }
  }

  int rseq = -1;                 // lane L holds seq[t-L] (reversed history)
  int counters = 1;
  bool alive = true, hasvar = false;
  float accE = 0.f, accLP = 0.f;
  int lenacc = 0;
  int row = H_T0;

  // first-step gumbel
  float g32;
  if (useG) {
    g32 = gtab[(size_t)(n << 6) + lane];
  } else {
    uint32_t kt0, kt1, b0, b1;
    threefry2x32(0u, 1234u, 0u, 0u, kt0, kt1);
    threefry2x32(kt0, kt1, 0u, (uint32_t)((n << 6) + lane), b0, b1);
    const uint32_t bits = b0 ^ b1;
    const float f = __uint_as_float((bits >> 9) | 0x3f800000u) - 1.0f;
    const float u = (f == 0.f) ? 1.17549435e-38f : f;
    g32 = -logf(-logf(u));
  }

  for (int t = 0; t < LMAX; ++t) {
    // prefetch next-step gumbel (independent load, issues early)
    float g_nxt = 0.f;
    if (t + 1 < LMAX) {
      if (useG) {
        g_nxt = gtab[(size_t)(t + 1) * (NSEQ * VV) + (n << 6) + lane];
      } else {
        uint32_t kt0, kt1, b0, b1;
        threefry2x32(0u, 1234u, 0u, (uint32_t)(t + 1), kt0, kt1);
        threefry2x32(kt0, kt1, 0u, (uint32_t)((n << 6) + lane), b0, b1);
        const uint32_t bits = b0 ^ b1;
        const float f = __uint_as_float((bits >> 9) | 0x3f800000u) - 1.0f;
        const float u = (f == 0.f) ? 1.17549435e-38f : f;
        g_nxt = -logf(-logf(u));
      }
    }

    // ---- logits x[lane] for this row
    float x;
    if (useX) {
      x = Xtab[(size_t)row * VV + lane];         // wave-uniform row, L2 hit
    } else {
      // fallback: compute h in-wave (f64 tanh) then dot via readlane
      float hreg[8];
#pragma unroll
      for (int i = 0; i < 8; ++i) {
        float ax;
        if (row == H_T0) {
          ax = xw[i];
        } else {
          const int p  = row / 65 - 1;
          const int sb = row % 65 - 1;
          ax = 0.f;
          if (p >= 0) ax = Wx[(size_t)p * HID + i * 64 + lane];
          if (sb >= 0) ax += Wx[(size_t)(VV + sb) * HID + i * 64 + lane];
        }
        hreg[i] = (float)tanh((double)(ax + hc[i]));
      }
      float acc = 0.f;
#pragma unroll
      for (int i = 0; i < 8; ++i) {
        for (int j = 0; j < 64; ++j) {
          const float hk = __int_as_float(
              __builtin_amdgcn_readlane(__float_as_int(hreg[i]), j));
          acc = fmaf(hk, Wp[(size_t)(i * 64 + j) * VV + lane], acc);
        }
      }
      x = acc + bp_v;
    }

    // ---- decision
    const int tot = t + counters;
    bool keep = true;
    if (zero_v && tot < MINLEN) keep = false;
    if (two_v && (tot + 2 > LMAX)) keep = false;
    if (one_v && (tot + 1 > LMAX)) keep = false;
    if (const_v && !hasvar && (counters == 1)) keep = false;

    const float e  = expf(x);
    const float ek = keep ? e : 0.f;
    float val = keep ? (g32 + x) : -__builtin_inff();

    // fused butterfly: S2 sum, dot sum, max — 3 interleaved chains
    float s2 = ek, dd = ek * x, mv = val;
#pragma unroll
    for (int off = 32; off >= 1; off >>= 1) {
      s2 += __shfl_xor(s2, off, 64);
      dd += __shfl_xor(dd, off, 64);
      mv = fmaxf(mv, __shfl_xor(mv, off, 64));
    }
    const unsigned long long win = __ballot(val == mv);
    const int token = __ffsll((long long)win) - 1;

    const bool tk2 = (two_mask >> token) & 1ull;
    const bool tk1 = (one_mask >> token) & 1ull;
    const bool tkv = (var_mask >> token) & 1ull;

    // reversed-history shift: rseq[lane] = seq[t-lane]
    const int up = __shfl_up(rseq, 1, 64);
    rseq = (lane == 0) ? token : up;

    // parent/sibling via ballot+popcount (DS-free prefix sum)
    const bool vld = lane <= t;
    const int tkl = rseq & 63;
    const unsigned long long twoB = __ballot(vld && ((two_mask >> tkl) & 1ull));
    const unsigned long long oneB = __ballot(vld && ((one_mask >> tkl) & 1ull));
    const unsigned long long mle = (2ull << lane) - 1ull;   // lane63 -> ~0
    const int c = 2 * __popcll(twoB & mle) + __popcll(oneB & mle) - (lane + 1);
    const unsigned long long hb = __ballot(vld && (c == 0));

    int parent, sib;
    if (tk2 || tk1) { parent = token; sib = -1; }
    else if (hb == 0ull) { parent = -1; sib = -1; }
    else {
      int kf = __ffsll((long long)hb) - 1;
      kf = __builtin_amdgcn_readfirstlane(kf);
      parent = __builtin_amdgcn_readlane(rseq, kf);
      sib = (kf == 0) ? -1 : __builtin_amdgcn_readlane(rseq, kf - 1);
    }
    row = (parent + 1) * 65 + (sib + 1);

    // stats: lp = x_tok - logS2 ; ent = logS2 - dot/S2
    const float logS2 = logf(s2);
    const int tok_u = __builtin_amdgcn_readfirstlane(token);
    const float x_tok =
        __int_as_float(__builtin_amdgcn_readlane(__float_as_int(x), tok_u));
    const float lp  = x_tok - logS2;
    const float ent = logS2 - dd / s2;

    counters += -1 + 2 * (int)tk2 + (int)tk1;
    alive = alive && (counters > 0);
    if (alive) { accE += ent; accLP += lp; lenacc++; }
    hasvar = hasvar || tkv;

    g32 = g_nxt;
  }

  // ---- outputs (f32): [seq (2048x64) | lengths | ents | lps]
  out[(size_t)n * LMAX + (63 - lane)] = (float)rseq;  // un-reverse
  if (lane == 0) {
    out[(size_t)NSEQ * LMAX + n]       = (float)(lenacc + 1);
    out[(size_t)NSEQ * (LMAX + 1) + n] = accE;
    out[(size_t)NSEQ * (LMAX + 2) + n] = accLP;
  }
}

extern "C" void kernel_launch(void *const *d_in, const int *in_sizes, int n_in,
                              void *d_out, int out_size, void *d_ws, size_t ws_size,
                              hipStream_t stream) {
  (void)n_in; (void)out_size;
  const float *input_init  = (const float *)d_in[0];
  const float *hidden_init = (const float *)d_in[1];
  const float *Wx = (const float *)d_in[2];
  const float *Wh = (const float *)d_in[3];
  const float *b  = (const float *)d_in[4];
  const float *Wp = (const float *)d_in[5];
  const float *bp = (const float *)d_in[6];
  const int *two_arr = (const int *)d_in[7];
  const int *one_arr = (const int *)d_in[8];
  const int *var_arr = (const int *)d_in[9];
  const int n2 = in_sizes[7], n1 = in_sizes[8], nv = in_sizes[9];

  // workspace layout: [hconst 2KB | xw0 2KB | X 1.08MB | g(f32) 33.5MB]
  const size_t offX = 4096;
  const size_t szX  = (size_t)H_ROWS * VV * sizeof(float);
  const size_t offG = offX + szX;                  // ~1.086 MB
  const size_t szG  = (size_t)LMAX * NSEQ * VV * sizeof(float);
  const int useX = (ws_size >= offG) ? 1 : 0;
  const int useG = (ws_size >= offG + szG) ? 1 : 0;

  float *hconst = (float *)d_ws;
  float *xw0    = hconst + HID;
  float *Xtab   = (float *)((char *)d_ws + offX);
  float *gtab   = (float *)((char *)d_ws + offG);
  float *out    = (float *)d_out;

  rnn_precompute<<<8, 64, 0, stream>>>(input_init, hidden_init, Wx, Wh, b,
                                       hconst, xw0);
  if (useX)
    rnn_xtable<<<H_ROWS, 512, 0, stream>>>(Wx, Wp, bp, hconst, xw0, Xtab);
  if (useG)
    rnn_gumbel_table<<<dim3((NSEQ * VV) / 256, LMAX), 256, 0, stream>>>(gtab);

  rnn_sampler<<<NSEQ, 64, 0, stream>>>(Wx, Wp, bp, hconst, xw0,
                                       two_arr, n2, one_arr, n1,
                                       var_arr, nv,
                                       Xtab, gtab, useX, useG, out);
}

// Round 14
// 133.229 us; speedup vs baseline: 24.8779x; 1.2490x over previous
//
#include <hip/hip_runtime.h>
#include <stdint.h>
#include <math.h>

#define NSEQ   2048
#define VV     64
#define HID    512
#define LMAX   64
#define MINLEN 4
#define H_ROWS 4226   // 65*65 (parent,sib) rows + 1 row for t==0
#define H_T0   4225

// ---------------- threefry2x32 (JAX/Random123, 20 rounds; KAT-verified) ----
__device__ __forceinline__ uint32_t rotl32(uint32_t x, int r) {
  return (x << r) | (x >> (32 - r));
}
__device__ __forceinline__ void threefry2x32(uint32_t ks0, uint32_t ks1,
                                             uint32_t x0, uint32_t x1,
                                             uint32_t &o0, uint32_t &o1) {
  uint32_t ks2 = ks0 ^ ks1 ^ 0x1BD11BDAu;
  x0 += ks0; x1 += ks1;
#define TF_RND(r) { x0 += x1; x1 = rotl32(x1, (r)); x1 ^= x0; }
  TF_RND(13) TF_RND(15) TF_RND(26) TF_RND(6)
  x0 += ks1; x1 += ks2 + 1u;
  TF_RND(17) TF_RND(29) TF_RND(16) TF_RND(24)
  x0 += ks2; x1 += ks0 + 2u;
  TF_RND(13) TF_RND(15) TF_RND(26) TF_RND(6)
  x0 += ks0; x1 += ks1 + 3u;
  TF_RND(17) TF_RND(29) TF_RND(16) TF_RND(24)
  x0 += ks1; x1 += ks2 + 4u;
  TF_RND(13) TF_RND(15) TF_RND(26) TF_RND(6)
  x0 += ks2; x1 += ks0 + 5u;
#undef TF_RND
  o0 = x0; o1 = x1;
}

// gumbel(t, idx): bit-identical to the (verified) R8-R13 realization
__device__ __forceinline__ float gumbel_of(uint32_t t, uint32_t idx) {
  uint32_t kt0, kt1, b0, b1;
  threefry2x32(0u, 1234u, 0u, t, kt0, kt1);
  threefry2x32(kt0, kt1, 0u, idx, b0, b1);
  const uint32_t bits = b0 ^ b1;
  const float f = __uint_as_float((bits >> 9) | 0x3f800000u) - 1.0f;
  const float u = (f == 0.f) ? 1.17549435e-38f : f;
  return -logf(-logf(u));
}

// ---------------- DPP wave reductions (no DS ops) ----------------
// row_ror:n = 0x120|n ; row_bcast15 = 0x142 ; row_bcast31 = 0x143
template <int CTRL>
__device__ __forceinline__ float dppf(float v) {
  return __int_as_float(__builtin_amdgcn_update_dpp(
      __float_as_int(v), __float_as_int(v), CTRL, 0xF, 0xF, false));
}
// full-wave max, broadcast via readlane(63). Order-invariant -> exact.
__device__ __forceinline__ float wave_max_bcast(float v) {
  v = fmaxf(v, dppf<0x121>(v));
  v = fmaxf(v, dppf<0x122>(v));
  v = fmaxf(v, dppf<0x124>(v));
  v = fmaxf(v, dppf<0x128>(v));
  v = fmaxf(v, dppf<0x142>(v));   // row0->row1, row2->row3 (others: fmax(v,v))
  v = fmaxf(v, dppf<0x143>(v));   // rows01 -> rows23
  return __int_as_float(__builtin_amdgcn_readlane(__float_as_int(v), 63));
}
// full-wave sum; lanes 0-47 hold garbage partials, lane 63 holds the total.
__device__ __forceinline__ float wave_sum_bcast(float v) {
  v += dppf<0x121>(v);
  v += dppf<0x122>(v);
  v += dppf<0x124>(v);
  v += dppf<0x128>(v);
  v += dppf<0x142>(v);
  v += dppf<0x143>(v);
  return __int_as_float(__builtin_amdgcn_readlane(__float_as_int(v), 63));
}

// ---- precompute (f64 accumulate, f32 store): hconst = h0@Wh + b ; xw0 ----
__global__ void rnn_precompute(const float *__restrict__ input_init,
                               const float *__restrict__ hidden_init,
                               const float *__restrict__ Wx,
                               const float *__restrict__ Wh,
                               const float *__restrict__ b,
                               float *__restrict__ hconst,
                               float *__restrict__ xw0) {
  const int k = blockIdx.x * 64 + threadIdx.x;
  if (k >= HID) return;
  double acc = 0.0;
  for (int j = 0; j < HID; ++j)
    acc = fma((double)hidden_init[j], (double)Wh[(size_t)j * HID + k], acc);
  hconst[k] = (float)(acc + (double)b[k]);
  double a2 = 0.0;
  for (int j = 0; j < 2 * VV; ++j)
    a2 = fma((double)input_init[j], (double)Wx[(size_t)j * HID + k], a2);
  xw0[k] = (float)a2;
}

// ---- X table: row r -> logits x[v] = H[r]·Wp[:,v] + bp[v] ----
// tanhf (<=1ulp, inside the np<->XLA tanh disagreement band); f64 dot accum.
__global__ __launch_bounds__(512) void rnn_xtable(
    const float *__restrict__ Wx, const float *__restrict__ Wp,
    const float *__restrict__ bp,
    const float *__restrict__ hconst, const float *__restrict__ xw0,
    float *__restrict__ X) {
  __shared__ float  smh[HID];
  __shared__ double smpart[8][VV];

  const int r   = blockIdx.x;
  const int tid = threadIdx.x;

  {
    float ax;
    if (r == H_T0) {
      ax = xw0[tid];
    } else {
      const int p = r / 65 - 1;
      const int s = r % 65 - 1;
      ax = 0.f;
      if (p >= 0) ax = Wx[(size_t)p * HID + tid];
      if (s >= 0) ax += Wx[(size_t)(VV + s) * HID + tid];
    }
    smh[tid] = tanhf(ax + hconst[tid]);
  }
  __syncthreads();

  const int v  = tid & 63;
  const int sl = tid >> 6;
  double acc = 0.0;
  for (int k = sl * 64; k < sl * 64 + 64; ++k)
    acc = fma((double)smh[k], (double)Wp[(size_t)k * VV + v], acc);
  smpart[sl][v] = acc;
  __syncthreads();

  if (tid < VV) {
    double s = 0.0;
#pragma unroll
    for (int i = 0; i < 8; ++i) s += smpart[i][tid];
    X[(size_t)r * VV + tid] = (float)(s + (double)bp[tid]);
  }
}

// --------- main sampler: 1 wave = 1 seq, zero LDS, zero DS ops -----
__global__ __launch_bounds__(64) void rnn_sampler(
    const float *__restrict__ Wx, const float *__restrict__ Wp,
    const float *__restrict__ bp,
    const float *__restrict__ hconst_g, const float *__restrict__ xw0_g,
    const int *__restrict__ two_arr, int n2,
    const int *__restrict__ one_arr, int n1,
    const int *__restrict__ var_arr, int nv,
    const float *__restrict__ Xtab, int useX,
    float *__restrict__ out) {
  const int lane = threadIdx.x;   // = token id v
  const int n    = blockIdx.x;    // sequence id

  bool isTwo = false, isOne = false, isVar = false;
  for (int j = 0; j < n2; ++j) isTwo |= (lane == two_arr[j]);
  for (int j = 0; j < n1; ++j) isOne |= (lane == one_arr[j]);
  for (int j = 0; j < nv; ++j) isVar |= (lane == var_arr[j]);
  const unsigned long long two_mask = __ballot(isTwo);
  const unsigned long long one_mask = __ballot(isOne);
  const unsigned long long var_mask = __ballot(isVar);
  const bool two_v   = (two_mask >> lane) & 1ull;
  const bool one_v   = (one_mask >> lane) & 1ull;
  const bool zero_v  = !(two_v || one_v);
  const bool const_v = zero_v && !((var_mask >> lane) & 1ull);
  const float bp_v   = bp[lane];

  // fallback-only per-lane slices (k = 64*i + lane)
  float hc[8], xw[8];
  if (!useX) {
#pragma unroll
    for (int i = 0; i < 8; ++i) {
      hc[i] = hconst_g[i * 64 + lane];
      xw[i] = xw0_g[i * 64 + lane];
    }
  }

  int myseq = -1;                 // lane t holds seq[t]
  unsigned long long twoHist = 0ull, oneHist = 0ull; // bit L = arity of seq[t-L]
  int counters = 1;
  bool alive = true, hasvar = false;
  float accE = 0.f, accLP = 0.f;
  int lenacc = 0;
  int row = H_T0;

  float g32 = gumbel_of(0u, (uint32_t)((n << 6) + lane));

  for (int t = 0; t < LMAX; ++t) {
    // next-step gumbel: independent -> overlaps the dependent X load
    const float g_nxt =
        (t + 1 < LMAX) ? gumbel_of((uint32_t)(t + 1),
                                   (uint32_t)((n << 6) + lane)) : 0.f;

    // ---- logits x[lane] for this row
    float x;
    if (useX) {
      x = Xtab[(size_t)row * VV + lane];        // wave-uniform row, L2-hot
    } else {
      float hreg[8];
#pragma unroll
      for (int i = 0; i < 8; ++i) {
        float ax;
        if (row == H_T0) {
          ax = xw[i];
        } else {
          const int p  = row / 65 - 1;
          const int sb = row % 65 - 1;
          ax = 0.f;
          if (p >= 0) ax = Wx[(size_t)p * HID + i * 64 + lane];
          if (sb >= 0) ax += Wx[(size_t)(VV + sb) * HID + i * 64 + lane];
        }
        hreg[i] = (float)tanh((double)(ax + hc[i]));
      }
      float acc = 0.f;
#pragma unroll
      for (int i = 0; i < 8; ++i) {
        for (int j = 0; j < 64; ++j) {
          const float hk = __int_as_float(
              __builtin_amdgcn_readlane(__float_as_int(hreg[i]), j));
          acc = fmaf(hk, Wp[(size_t)(i * 64 + j) * VV + lane], acc);
        }
      }
      x = acc + bp_v;
    }

    // ---- mask + sample (argmax of gumbel + logit, shift-invariant)
    const int tot = t + counters;
    bool keep = true;
    if (zero_v && tot < MINLEN) keep = false;
    if (two_v && (tot + 2 > LMAX)) keep = false;
    if (one_v && (tot + 1 > LMAX)) keep = false;
    if (const_v && !hasvar && (counters == 1)) keep = false;

    const float val = keep ? (g32 + x) : -__builtin_inff();
    const float mv = wave_max_bcast(val);
    const unsigned long long win = __ballot(val == mv);
    const int token = __ffsll((long long)win) - 1;

    const bool tk2 = (two_mask >> token) & 1ull;
    const bool tk1 = (one_mask >> token) & 1ull;
    const bool tkv = (var_mask >> token) & 1ull;

    if (lane == t) myseq = token;
    twoHist = (twoHist << 1) | (unsigned long long)(tk2 ? 1 : 0);
    oneHist = (oneHist << 1) | (unsigned long long)(tk1 ? 1 : 0);

    counters += -1 + 2 * (int)tk2 + (int)tk1;
    const bool aliveN = alive && (counters > 0);

    // ---- stats only while alive (wave-uniform branch; loose tolerance)
    if (alive) {
      const float e  = expf(x);
      const float ek = keep ? e : 0.f;
      const float s2 = wave_sum_bcast(ek);
      const float dd = wave_sum_bcast(ek * x);
      const float logS2 = logf(s2);
      const int tok_u = __builtin_amdgcn_readfirstlane(token);
      const float x_tok = __int_as_float(
          __builtin_amdgcn_readlane(__float_as_int(x), tok_u));
      if (aliveN) {
        accLP += x_tok - logS2;
        accE  += logS2 - dd / s2;
        lenacc++;
      }
    }
    alive = aliveN;
    hasvar = hasvar || tkv;

    // ---- parent/sibling from scalar arity-history words (no DS ops)
    int parent, sib;
    if (tk2 || tk1) {
      parent = token; sib = -1;
    } else {
      const unsigned long long mle = (2ull << lane) - 1ull; // lane63 -> ~0
      const int c = 2 * __popcll(twoHist & mle) + __popcll(oneHist & mle) -
                    (lane + 1);
      const unsigned long long hb = __ballot((lane <= t) && (c == 0));
      if (hb == 0ull) {
        parent = -1; sib = -1;
      } else {
        int kf = __ffsll((long long)hb) - 1;
        kf = __builtin_amdgcn_readfirstlane(kf);
        parent = __builtin_amdgcn_readlane(myseq, t - kf);
        sib = (kf == 0) ? -1 : __builtin_amdgcn_readlane(myseq, t - kf + 1);
      }
    }
    row = (parent + 1) * 65 + (sib + 1);
    g32 = g_nxt;
  }

  // ---- outputs (f32): [seq (2048x64) | lengths | ents | lps]
  out[(size_t)n * LMAX + lane] = (float)myseq;
  if (lane == 0) {
    out[(size_t)NSEQ * LMAX + n]       = (float)(lenacc + 1);
    out[(size_t)NSEQ * (LMAX + 1) + n] = accE;
    out[(size_t)NSEQ * (LMAX + 2) + n] = accLP;
  }
}

extern "C" void kernel_launch(void *const *d_in, const int *in_sizes, int n_in,
                              void *d_out, int out_size, void *d_ws, size_t ws_size,
                              hipStream_t stream) {
  (void)n_in; (void)out_size;
  const float *input_init  = (const float *)d_in[0];
  const float *hidden_init = (const float *)d_in[1];
  const float *Wx = (const float *)d_in[2];
  const float *Wh = (const float *)d_in[3];
  const float *b  = (const float *)d_in[4];
  const float *Wp = (const float *)d_in[5];
  const float *bp = (const float *)d_in[6];
  const int *two_arr = (const int *)d_in[7];
  const int *one_arr = (const int *)d_in[8];
  const int *var_arr = (const int *)d_in[9];
  const int n2 = in_sizes[7], n1 = in_sizes[8], nv = in_sizes[9];

  // workspace layout: [hconst 2KB | xw0 2KB | X 1.08MB]
  const size_t offX = 4096;
  const size_t szX  = (size_t)H_ROWS * VV * sizeof(float);
  const int useX = (ws_size >= offX + szX) ? 1 : 0;

  float *hconst = (float *)d_ws;
  float *xw0    = hconst + HID;
  float *Xtab   = (float *)((char *)d_ws + offX);
  float *out    = (float *)d_out;

  rnn_precompute<<<8, 64, 0, stream>>>(input_init, hidden_init, Wx, Wh, b,
                                       hconst, xw0);
  if (useX)
    rnn_xtable<<<H_ROWS, 512, 0, stream>>>(Wx, Wp, bp, hconst, xw0, Xtab);

  rnn_sampler<<<NSEQ, 64, 0, stream>>>(Wx, Wp, bp, hconst, xw0,
                                       two_arr, n2, one_arr, n1,
                                       var_arr, nv, Xtab, useX, out);
}

// Round 15
// 102.788 us; speedup vs baseline: 32.2455x; 1.2962x over previous
//
#include <hip/hip_runtime.h>
#include <stdint.h>
#include <math.h>

#define NSEQ   2048
#define VV     64
#define HID    512
#define LMAX   64
#define MINLEN 4
#define H_ROWS 4226   // 65*65 (parent,sib) rows + 1 row for t==0
#define H_T0   4225

// ---------------- threefry2x32 (JAX/Random123, 20 rounds; KAT-verified) ----
__device__ __forceinline__ uint32_t rotl32(uint32_t x, int r) {
  return (x << r) | (x >> (32 - r));
}
__device__ __forceinline__ void threefry2x32(uint32_t ks0, uint32_t ks1,
                                             uint32_t x0, uint32_t x1,
                                             uint32_t &o0, uint32_t &o1) {
  uint32_t ks2 = ks0 ^ ks1 ^ 0x1BD11BDAu;
  x0 += ks0; x1 += ks1;
#define TF_RND(r) { x0 += x1; x1 = rotl32(x1, (r)); x1 ^= x0; }
  TF_RND(13) TF_RND(15) TF_RND(26) TF_RND(6)
  x0 += ks1; x1 += ks2 + 1u;
  TF_RND(17) TF_RND(29) TF_RND(16) TF_RND(24)
  x0 += ks2; x1 += ks0 + 2u;
  TF_RND(13) TF_RND(15) TF_RND(26) TF_RND(6)
  x0 += ks0; x1 += ks1 + 3u;
  TF_RND(17) TF_RND(29) TF_RND(16) TF_RND(24)
  x0 += ks1; x1 += ks2 + 4u;
  TF_RND(13) TF_RND(15) TF_RND(26) TF_RND(6)
  x0 += ks2; x1 += ks0 + 5u;
#undef TF_RND
  o0 = x0; o1 = x1;
}

// w = -logf(u) from the (verified) partitionable bit recipe; gumbel g = -log w
__device__ __forceinline__ float wgum(uint32_t k0, uint32_t k1, uint32_t idx) {
  uint32_t b0, b1;
  threefry2x32(k0, k1, 0u, idx, b0, b1);
  const uint32_t bits = b0 ^ b1;
  const float f = __uint_as_float((bits >> 9) | 0x3f800000u) - 1.0f;
  const float u = (f == 0.f) ? 1.17549435e-38f : f;
  return -logf(u);
}

// ---------------- DPP wave reductions (no DS ops) ----------------
template <int CTRL>
__device__ __forceinline__ float dppf(float v) {
  return __int_as_float(__builtin_amdgcn_update_dpp(
      __float_as_int(v), __float_as_int(v), CTRL, 0xF, 0xF, false));
}
__device__ __forceinline__ float wave_max_bcast(float v) {
  v = fmaxf(v, dppf<0x121>(v));
  v = fmaxf(v, dppf<0x122>(v));
  v = fmaxf(v, dppf<0x124>(v));
  v = fmaxf(v, dppf<0x128>(v));
  v = fmaxf(v, dppf<0x142>(v));
  v = fmaxf(v, dppf<0x143>(v));
  return __int_as_float(__builtin_amdgcn_readlane(__float_as_int(v), 63));
}
__device__ __forceinline__ float wave_sum_bcast(float v) {
  v += dppf<0x121>(v);
  v += dppf<0x122>(v);
  v += dppf<0x124>(v);
  v += dppf<0x128>(v);
  v += dppf<0x142>(v);
  v += dppf<0x143>(v);
  return __int_as_float(__builtin_amdgcn_readlane(__float_as_int(v), 63));
}

// ---- precompute: hconst, xw0 (f64 acc) + per-step threefry keys ktab ----
__global__ void rnn_precompute(const float *__restrict__ input_init,
                               const float *__restrict__ hidden_init,
                               const float *__restrict__ Wx,
                               const float *__restrict__ Wh,
                               const float *__restrict__ b,
                               float *__restrict__ hconst,
                               float *__restrict__ xw0,
                               uint32_t *__restrict__ ktab) {
  const int k = blockIdx.x * 64 + threadIdx.x;
  if (blockIdx.x == 0) {
    const int t = threadIdx.x;   // 64 threads = 64 steps
    uint32_t o0, o1;
    threefry2x32(0u, 1234u, 0u, (uint32_t)t, o0, o1);
    ktab[2 * t]     = o0;
    ktab[2 * t + 1] = o1;
  }
  if (k >= HID) return;
  double acc = 0.0;
  for (int j = 0; j < HID; ++j)
    acc = fma((double)hidden_init[j], (double)Wh[(size_t)j * HID + k], acc);
  hconst[k] = (float)(acc + (double)b[k]);
  double a2 = 0.0;
  for (int j = 0; j < 2 * VV; ++j)
    a2 = fma((double)input_init[j], (double)Wx[(size_t)j * HID + k], a2);
  xw0[k] = (float)a2;
}

// ---- X table: row r -> logits x[v] = H[r]·Wp[:,v] + bp[v] ----
// Early-exits rows whose parent is not an operator (provably unreachable:
// the backward-scan counter walks in unit steps from -1, so the first
// c==0 crossing is an arity-2 token; the override case is seq[t] operator).
__global__ __launch_bounds__(512) void rnn_xtable(
    const float *__restrict__ Wx, const float *__restrict__ Wp,
    const float *__restrict__ bp,
    const float *__restrict__ hconst, const float *__restrict__ xw0,
    const int *__restrict__ two_arr, int n2,
    const int *__restrict__ one_arr, int n1,
    float *__restrict__ X) {
  __shared__ float  smh[HID];
  __shared__ double smpart[8][VV];

  const int r   = blockIdx.x;
  const int tid = threadIdx.x;

  if (r != H_T0) {
    const int p = r / 65 - 1;
    if (p >= 0) {
      bool isOp = false;
      for (int j = 0; j < n2; ++j) isOp |= (p == two_arr[j]);
      for (int j = 0; j < n1; ++j) isOp |= (p == one_arr[j]);
      if (!isOp) return;          // unreachable row
    }
  }

  {
    float ax;
    if (r == H_T0) {
      ax = xw0[tid];
    } else {
      const int p = r / 65 - 1;
      const int s = r % 65 - 1;
      ax = 0.f;
      if (p >= 0) ax = Wx[(size_t)p * HID + tid];
      if (s >= 0) ax += Wx[(size_t)(VV + s) * HID + tid];
    }
    smh[tid] = tanhf(ax + hconst[tid]);
  }
  __syncthreads();

  const int v  = tid & 63;
  const int sl = tid >> 6;
  double acc = 0.0;
  for (int k = sl * 64; k < sl * 64 + 64; ++k)
    acc = fma((double)smh[k], (double)Wp[(size_t)k * VV + v], acc);
  smpart[sl][v] = acc;
  __syncthreads();

  if (tid < VV) {
    double s = 0.0;
#pragma unroll
    for (int i = 0; i < 8; ++i) s += smpart[i][tid];
    X[(size_t)r * VV + tid] = (float)(s + (double)bp[tid]);
  }
}

// --------- main sampler: 1 wave = 1 seq, zero LDS, zero DS ops -----
__global__ __launch_bounds__(64) void rnn_sampler(
    const float *__restrict__ Wx, const float *__restrict__ Wp,
    const float *__restrict__ bp,
    const float *__restrict__ hconst_g, const float *__restrict__ xw0_g,
    const int *__restrict__ two_arr, int n2,
    const int *__restrict__ one_arr, int n1,
    const int *__restrict__ var_arr, int nv,
    const float *__restrict__ Xtab, const uint32_t *__restrict__ ktab,
    int useX,
    float *__restrict__ out) {
  const int lane = threadIdx.x;   // = token id v
  const int n    = blockIdx.x;    // sequence id
  const uint32_t idx = (uint32_t)((n << 6) + lane);

  bool isTwo = false, isOne = false, isVar = false;
  for (int j = 0; j < n2; ++j) isTwo |= (lane == two_arr[j]);
  for (int j = 0; j < n1; ++j) isOne |= (lane == one_arr[j]);
  for (int j = 0; j < nv; ++j) isVar |= (lane == var_arr[j]);
  const unsigned long long two_mask = __ballot(isTwo);
  const unsigned long long one_mask = __ballot(isOne);
  const unsigned long long var_mask = __ballot(isVar);
  const bool two_v   = (two_mask >> lane) & 1ull;
  const bool one_v   = (one_mask >> lane) & 1ull;
  const bool zero_v  = !(two_v || one_v);
  const bool const_v = zero_v && !((var_mask >> lane) & 1ull);
  const float bp_v   = bp[lane];

  // fallback-only per-lane slices (k = 64*i + lane)
  float hc[8], xw[8];
  if (!useX) {
#pragma unroll
    for (int i = 0; i < 8; ++i) {
      hc[i] = hconst_g[i * 64 + lane];
      xw[i] = xw0_g[i * 64 + lane];
    }
  }

  int myseq = -1;                 // lane t holds seq[t]
  unsigned long long twoHist = 0ull, oneHist = 0ull;
  int counters = 1;
  bool alive = true, hasvar = false;
  float accE = 0.f, accLP = 0.f;
  int lenacc = 0;
  int row = H_T0;

  float w = wgum(ktab[0], ktab[1], idx);   // w = -log(u); gumbel = -log(w)

  for (int t = 0; t < LMAX; ++t) {
    // next-step w: independent work, overlaps the dependent X load
    float w_nxt = 1.f;
    if (t + 1 < LMAX)
      w_nxt = wgum(ktab[2 * (t + 1)], ktab[2 * (t + 1) + 1], idx);

    // ---- logits x[lane] for this row
    float x;
    if (useX) {
      x = Xtab[(size_t)row * VV + lane];        // wave-uniform row, L2-hot
    } else {
      float hreg[8];
#pragma unroll
      for (int i = 0; i < 8; ++i) {
        float ax;
        if (row == H_T0) {
          ax = xw[i];
        } else {
          const int p  = row / 65 - 1;
          const int sb = row % 65 - 1;
          ax = 0.f;
          if (p >= 0) ax = Wx[(size_t)p * HID + i * 64 + lane];
          if (sb >= 0) ax += Wx[(size_t)(VV + sb) * HID + i * 64 + lane];
        }
        hreg[i] = (float)tanh((double)(ax + hc[i]));
      }
      float acc = 0.f;
#pragma unroll
      for (int i = 0; i < 8; ++i) {
        for (int j = 0; j < 64; ++j) {
          const float hk = __int_as_float(
              __builtin_amdgcn_readlane(__float_as_int(hreg[i]), j));
          acc = fmaf(hk, Wp[(size_t)(i * 64 + j) * VV + lane], acc);
        }
      }
      x = acc + bp_v;
    }

    // ---- mask + sample: argmax(g+x) == argmax(expf(x)/w), monotone
    const int tot = t + counters;
    bool keep = true;
    if (zero_v && tot < MINLEN) keep = false;
    if (two_v && (tot + 2 > LMAX)) keep = false;
    if (one_v && (tot + 1 > LMAX)) keep = false;
    if (const_v && !hasvar && (counters == 1)) keep = false;

    const float ex  = expf(x);
    const float val = keep ? (ex / w) : 0.f;
    const float mv  = wave_max_bcast(val);
    const unsigned long long win = __ballot(val == mv);
    const int token = __ffsll((long long)win) - 1;

    const bool tk2 = (two_mask >> token) & 1ull;
    const bool tk1 = (one_mask >> token) & 1ull;
    const bool tkv = (var_mask >> token) & 1ull;

    if (lane == t) myseq = token;
    twoHist = (twoHist << 1) | (unsigned long long)(tk2 ? 1 : 0);
    oneHist = (oneHist << 1) | (unsigned long long)(tk1 ? 1 : 0);

    counters += -1 + 2 * (int)tk2 + (int)tk1;
    const bool aliveN = alive && (counters > 0);

    // ---- stats only while alive (wave-uniform branch; loose tolerance)
    if (alive) {
      const float ek = keep ? ex : 0.f;
      const float s2 = wave_sum_bcast(ek);
      const float dd = wave_sum_bcast(ek * x);
      const float logS2 = logf(s2);
      const int tok_u = __builtin_amdgcn_readfirstlane(token);
      const float x_tok = __int_as_float(
          __builtin_amdgcn_readlane(__float_as_int(x), tok_u));
      if (aliveN) {
        accLP += x_tok - logS2;
        accE  += logS2 - dd / s2;
        lenacc++;
      }
    }
    alive = aliveN;
    hasvar = hasvar || tkv;

    // ---- parent/sibling from scalar arity-history words (no DS ops)
    int parent, sib;
    if (tk2 || tk1) {
      parent = token; sib = -1;
    } else {
      const unsigned long long mle = (2ull << lane) - 1ull;
      const int c = 2 * __popcll(twoHist & mle) + __popcll(oneHist & mle) -
                    (lane + 1);
      const unsigned long long hb = __ballot((lane <= t) && (c == 0));
      if (hb == 0ull) {
        parent = -1; sib = -1;
      } else {
        int kf = __ffsll((long long)hb) - 1;
        kf = __builtin_amdgcn_readfirstlane(kf);
        parent = __builtin_amdgcn_readlane(myseq, t - kf);
        sib = (kf == 0) ? -1 : __builtin_amdgcn_readlane(myseq, t - kf + 1);
      }
    }
    row = (parent + 1) * 65 + (sib + 1);
    w = w_nxt;
  }

  // ---- outputs (f32): [seq (2048x64) | lengths | ents | lps]
  out[(size_t)n * LMAX + lane] = (float)myseq;
  if (lane == 0) {
    out[(size_t)NSEQ * LMAX + n]       = (float)(lenacc + 1);
    out[(size_t)NSEQ * (LMAX + 1) + n] = accE;
    out[(size_t)NSEQ * (LMAX + 2) + n] = accLP;
  }
}

extern "C" void kernel_launch(void *const *d_in, const int *in_sizes, int n_in,
                              void *d_out, int out_size, void *d_ws, size_t ws_size,
                              hipStream_t stream) {
  (void)n_in; (void)out_size;
  const float *input_init  = (const float *)d_in[0];
  const float *hidden_init = (const float *)d_in[1];
  const float *Wx = (const float *)d_in[2];
  const float *Wh = (const float *)d_in[3];
  const float *b  = (const float *)d_in[4];
  const float *Wp = (const float *)d_in[5];
  const float *bp = (const float *)d_in[6];
  const int *two_arr = (const int *)d_in[7];
  const int *one_arr = (const int *)d_in[8];
  const int *var_arr = (const int *)d_in[9];
  const int n2 = in_sizes[7], n1 = in_sizes[8], nv = in_sizes[9];

  // ws layout: [hconst 2KB | xw0 2KB | ktab 512B @4096 | X 1.08MB @8192]
  const size_t offK = 4096;
  const size_t offX = 8192;
  const size_t szX  = (size_t)H_ROWS * VV * sizeof(float);
  const int useX = (ws_size >= offX + szX) ? 1 : 0;

  float    *hconst = (float *)d_ws;
  float    *xw0    = hconst + HID;
  uint32_t *ktab   = (uint32_t *)((char *)d_ws + offK);
  float    *Xtab   = (float *)((char *)d_ws + offX);
  float    *out    = (float *)d_out;

  rnn_precompute<<<8, 64, 0, stream>>>(input_init, hidden_init, Wx, Wh, b,
                                       hconst, xw0, ktab);
  if (useX)
    rnn_xtable<<<H_ROWS, 512, 0, stream>>>(Wx, Wp, bp, hconst, xw0,
                                           two_arr, n2, one_arr, n1, Xtab);

  rnn_sampler<<<NSEQ, 64, 0, stream>>>(Wx, Wp, bp, hconst, xw0,
                                       two_arr, n2, one_arr, n1,
                                       var_arr, nv, Xtab, ktab, useX, out);
}